// Round 8
// baseline (404.111 us; speedup 1.0000x reference)
//
#include <hip/hip_runtime.h>
#include <hip/hip_bf16.h>
#include <math.h>

// Problem constants
#define B_   8
#define T_   4096
#define D_   768
#define R_   16
#define DB_  256
#define N_   (B_ * T_)      // 32768 tokens
#define NC_  64             // scan chunks per sequence
#define L_   (T_ / NC_)     // 64 steps per chunk
#define NKS_ (D_ / 32)      // 24 K-steps of 32

typedef __attribute__((ext_vector_type(8))) short bf16x8;
typedef __attribute__((ext_vector_type(4))) float f32x4;

__device__ __forceinline__ float gelu_exact(float x) {
    return 0.5f * x * (1.0f + erff(x * 0.70710678118654752f));
}
__device__ __forceinline__ float sigmoidf_(float x) {
    return 1.0f / (1.0f + expf(-x));
}
__device__ __forceinline__ float bf2f(unsigned short u) {
    return __uint_as_float(((unsigned)u) << 16);
}
__device__ __forceinline__ unsigned short f2bf(float f) {
    __hip_bfloat16 h = __float2bfloat16(f);   // RNE
    return *(unsigned short*)&h;
}
__device__ __forceinline__ bf16x8 pack8(float4 a, float4 b) {
    bf16x8 r;
    r[0] = (short)f2bf(a.x); r[1] = (short)f2bf(a.y);
    r[2] = (short)f2bf(a.z); r[3] = (short)f2bf(a.w);
    r[4] = (short)f2bf(b.x); r[5] = (short)f2bf(b.y);
    r[6] = (short)f2bf(b.z); r[7] = (short)f2bf(b.w);
    return r;
}

// async global->LDS, 16B per lane. LDS dest = wave-uniform base + lane*16.
__device__ __forceinline__ void gload16(const unsigned short* g, unsigned short* l) {
    __builtin_amdgcn_global_load_lds(
        (const __attribute__((address_space(1))) unsigned int*)(const void*)g,
        (__attribute__((address_space(3))) unsigned int*)(void*)l,
        16, 0, 0);
}

// ---------------------------------------------------------------------------
// Geometry: 256 threads = 4 waves. Block tile = 128 (A rows) x BN (B rows),
// BN = NB*64. Wave tile = 128 x (NB*16): each wave owns an n-slice.
// FLOP/LDS-read-byte = 128*64/(128+64) = 42.7 for NB=4 (vs 32 for 64x64).
// Staging: source quad swizzled (q ^= (row>>1)&3), LDS dest linear (rule 21).
// Loads/thread/K-step = 2 (A) + NB (B).
// ---------------------------------------------------------------------------
template <int NB>
__device__ __forceinline__ void stage_ab(const unsigned short* __restrict__ A,
                                         const unsigned short* __restrict__ Bm,
                                         int row0, int col0, int k0,
                                         unsigned short* buf, int w, int l) {
#pragma unroll
    for (int j = 0; j < 2; ++j) {               // A: 128x32 = 512 chunks
        int i = ((w * 2 + j) << 6) + l;
        int row = i >> 2, q = i & 3;
        int qs = q ^ ((row >> 1) & 3);
        gload16(A + (size_t)(row0 + row) * D_ + k0 + qs * 8, buf + ((w * 2 + j) << 9));
    }
    unsigned short* bl = buf + 4096;
#pragma unroll
    for (int j = 0; j < NB; ++j) {              // B: (NB*64)x32 = NB*256 chunks
        int i = ((w * NB + j) << 6) + l;
        int row = i >> 2, q = i & 3;
        int qs = q ^ ((row >> 1) & 3);
        gload16(Bm + (size_t)(col0 + row) * D_ + k0 + qs * 8, bl + ((w * NB + j) << 9));
    }
}

// swizzled LDS fragment read: 8 bf16 for mfma_16x16x32 (bank-conflict-free)
__device__ __forceinline__ bf16x8 frag_read(const unsigned short* lds, int row, int lq) {
    int q = lq ^ ((row >> 1) & 3);
    return *(const bf16x8*)(lds + row * 32 + q * 8);
}

template <int NB>
__device__ __forceinline__ void tile_mfma(const unsigned short* buf,
                                          int wcol, int lr, int lq,
                                          f32x4 acc[8][NB]) {
    const unsigned short* la = buf;
    const unsigned short* lb = buf + 4096;
    bf16x8 b[NB];
#pragma unroll
    for (int n = 0; n < NB; n++) b[n] = frag_read(lb, wcol + n * 16 + lr, lq);
    __builtin_amdgcn_s_setprio(1);      // T5
#pragma unroll
    for (int m = 0; m < 8; m++) {
        bf16x8 a = frag_read(la, m * 16 + lr, lq);
#pragma unroll
        for (int n = 0; n < NB; n++)
            acc[m][n] = __builtin_amdgcn_mfma_f32_16x16x32_bf16(a, b[n], acc[m][n], 0, 0, 0);
    }
    __builtin_amdgcn_s_setprio(0);
}

template <int NB>
__device__ __forceinline__ void kloop_prologue(const unsigned short* __restrict__ A,
                                               const unsigned short* __restrict__ Bm,
                                               int row0, int col0,
                                               unsigned short* lds, int w, int l) {
    constexpr int BUFE = 4096 + NB * 2048;
    stage_ab<NB>(A, Bm, row0, col0, 0,  lds,        w, l);
    stage_ab<NB>(A, Bm, row0, col0, 32, lds + BUFE, w, l);
}

// ---------------------------------------------------------------------------
// K-loop (K=768), 3-deep pipeline, counted vmcnt: (2+NB) loads/thread/K-step,
// 2 tiles in flight; wait oldest (2+NB) -> own tile landed. Never drains to 0
// in the main loop.
// ---------------------------------------------------------------------------
template <int NB, bool DO_PROLOGUE>
__device__ __forceinline__ void kloop3(const unsigned short* __restrict__ A,
                                       const unsigned short* __restrict__ Bm,
                                       int row0, int col0,
                                       unsigned short* lds,   // 3 * BUFE
                                       int w, int l, f32x4 acc[8][NB]) {
    const int lr = l & 15, lq = l >> 4;
    const int wcol = w * NB * 16;
    constexpr int BUFE = 4096 + NB * 2048;

    if (DO_PROLOGUE) kloop_prologue<NB>(A, Bm, row0, col0, lds, w, l);

#pragma unroll 3
    for (int t = 0; t < NKS_ - 2; ++t) {
        if constexpr (NB == 4) asm volatile("s_waitcnt vmcnt(6)" ::: "memory");
        else                   asm volatile("s_waitcnt vmcnt(4)" ::: "memory");
        __builtin_amdgcn_s_barrier();
        __builtin_amdgcn_sched_barrier(0);
        stage_ab<NB>(A, Bm, row0, col0, (t + 2) * 32, lds + ((t + 2) % 3) * BUFE, w, l);
        tile_mfma<NB>(lds + (t % 3) * BUFE, wcol, lr, lq, acc);
    }
    if constexpr (NB == 4) asm volatile("s_waitcnt vmcnt(6)" ::: "memory");
    else                   asm volatile("s_waitcnt vmcnt(4)" ::: "memory");
    __builtin_amdgcn_s_barrier();
    __builtin_amdgcn_sched_barrier(0);
    tile_mfma<NB>(lds + ((NKS_ - 2) % 3) * BUFE, wcol, lr, lq, acc);
    asm volatile("s_waitcnt vmcnt(0)" ::: "memory");
    __builtin_amdgcn_s_barrier();
    __builtin_amdgcn_sched_barrier(0);
    tile_mfma<NB>(lds + ((NKS_ - 1) % 3) * BUFE, wcol, lr, lq, acc);
}

// chunked XCD swizzle (nwg % 8 == 0), then col-fastest decode
__device__ __forceinline__ void tile_decode(int nwg, int ncol, int& rowt, int& colt) {
    int bid = blockIdx.x;
    int cpx = nwg >> 3;
    int swz = (bid & 7) * cpx + (bid >> 3);
    colt = swz % ncol;
    rowt = swz / ncol;
}

// ---------------------------------------------------------------------------
// E1 GEMM + alpha partials (H never materialized). Block 128x128, NB=2,
// grid 512 (2 col x 256 row), 3 blocks/CU -> full chip in one generation.
// ---------------------------------------------------------------------------
__global__ __launch_bounds__(256, 3)
void gemm_e1_alpha(const unsigned short* __restrict__ Xb,
                   const unsigned short* __restrict__ Wb,
                   const float* __restrict__ bias,
                   const float* __restrict__ E2w,
                   float* __restrict__ alpha_acc) {
    __shared__ unsigned short lds[3 * (4096 + 2 * 2048)];
    const int t = threadIdx.x, l = t & 63, w = t >> 6;
    int rowt, colt;
    tile_decode(512, 2, rowt, colt);
    const int row0 = rowt * 128, col0 = colt * 128;
    const int lr = l & 15, lq = l >> 4;
    const int wcol = w * 32;
    f32x4 acc[8][2] = {};
    kloop3<2, true>(Xb, Wb, row0, col0, lds, w, l, acc);

    float bia[2], e2v[3][2];
#pragma unroll
    for (int n = 0; n < 2; n++) {
        int col = col0 + wcol + n * 16 + lr;
        bia[n] = bias[col];
#pragma unroll
        for (int c = 0; c < 3; c++) e2v[c][n] = E2w[c * DB_ + col];
    }
#pragma unroll
    for (int m = 0; m < 8; m++)
#pragma unroll
        for (int r = 0; r < 4; r++) {
            float p0 = 0.f, p1 = 0.f, p2 = 0.f;
#pragma unroll
            for (int n = 0; n < 2; n++) {
                float h = gelu_exact(acc[m][n][r] + bia[n]);
                p0 = fmaf(h, e2v[0][n], p0);
                p1 = fmaf(h, e2v[1][n], p1);
                p2 = fmaf(h, e2v[2][n], p2);
            }
#pragma unroll
            for (int s = 1; s < 16; s <<= 1) {
                p0 += __shfl_xor(p0, s);
                p1 += __shfl_xor(p1, s);
                p2 += __shfl_xor(p2, s);
            }
            if (lr == 0) {
                int row = row0 + m * 16 + lq * 4 + r;
                atomicAdd(&alpha_acc[(size_t)row * 3 + 0], p0);
                atomicAdd(&alpha_acc[(size_t)row * 3 + 1], p1);
                atomicAdd(&alpha_acc[(size_t)row * 3 + 2], p2);
            }
        }
}

// ---------------------------------------------------------------------------
// Fused: gate = sigmoid(Xb@G^T+Gb) (packed bf16 in regs), then
//        out = x_bf + gelu(Sb@C^T) * gate.
// Block 128x256, NB=4, grid 768 (3 col x 256 row), 2 blocks/CU.
// ---------------------------------------------------------------------------
__global__ __launch_bounds__(256, 2)
void gemm_fused_out(const unsigned short* __restrict__ Xb,
                    const unsigned short* __restrict__ Gwb,
                    const unsigned short* __restrict__ Sb,
                    const unsigned short* __restrict__ Cwb,
                    const float* __restrict__ Gbias,
                    float* __restrict__ out) {
    __shared__ unsigned short lds[3 * (4096 + 4 * 2048)];
    const int t = threadIdx.x, l = t & 63, w = t >> 6;
    int rowt, colt;
    tile_decode(768, 3, rowt, colt);
    const int row0 = rowt * 128, col0 = colt * 256;
    const int lr = l & 15, lq = l >> 4;
    const int wcol = w * 64;

    float gb[4];
#pragma unroll
    for (int n = 0; n < 4; n++) gb[n] = Gbias[col0 + wcol + n * 16 + lr];

    f32x4 acc[8][4] = {};
    kloop3<4, true>(Xb, Gwb, row0, col0, lds, w, l, acc);

    // issue kloop-C prologue now: HBM latency hides under the gate pack.
    // Safe: all buffer readers passed the final kloop-G barriers.
    kloop_prologue<4>(Sb, Cwb, row0, col0, lds, w, l);

    unsigned int gp[8][4][2];
#pragma unroll
    for (int m = 0; m < 8; m++)
#pragma unroll
        for (int n = 0; n < 4; n++) {
            gp[m][n][0] = (unsigned)f2bf(sigmoidf_(acc[m][n][0] + gb[n]))
                        | ((unsigned)f2bf(sigmoidf_(acc[m][n][1] + gb[n])) << 16);
            gp[m][n][1] = (unsigned)f2bf(sigmoidf_(acc[m][n][2] + gb[n]))
                        | ((unsigned)f2bf(sigmoidf_(acc[m][n][3] + gb[n])) << 16);
            acc[m][n] = (f32x4){0.f, 0.f, 0.f, 0.f};
        }

    kloop3<4, false>(Sb, Cwb, row0, col0, lds, w, l, acc);

#pragma unroll
    for (int m = 0; m < 8; m++)
#pragma unroll
        for (int n = 0; n < 4; n++) {
            int col = col0 + wcol + n * 16 + lr;
#pragma unroll
            for (int r = 0; r < 4; r++) {
                int row = row0 + m * 16 + lq * 4 + r;
                size_t o = (size_t)row * D_ + col;
                float g = bf2f((unsigned short)(gp[m][n][r >> 1] >> ((r & 1) * 16)));
                out[o] = bf2f(Xb[o]) + gelu_exact(acc[m][n][r]) * g;
            }
        }
}

// ---------------------------------------------------------------------------
// Fused cvt + Z: x_bf = bf16(x);  Z = x_bf @ V^T (V converted on the fly).
// ---------------------------------------------------------------------------
__global__ __launch_bounds__(256)
void cvtz_kernel(const float* __restrict__ X, const float* __restrict__ Vw,
                 unsigned short* __restrict__ Xb, float* __restrict__ Z) {
    const int t = threadIdx.x, l = t & 63, w = t >> 6;
    const int lr = l & 15, lq = l >> 4;
    const int tok0 = (blockIdx.x * 4 + w) * 16;
    const float* xrow = X  + (size_t)(tok0 + lr) * D_;
    const float* vrow = Vw + (size_t)lr * D_;
    f32x4 acc = {};
#pragma unroll 4
    for (int k0 = 0; k0 < D_; k0 += 32) {
        int k = k0 + lq * 8;
        float4 xa = *(const float4*)&xrow[k];
        float4 xb = *(const float4*)&xrow[k + 4];
        float4 va = *(const float4*)&vrow[k];
        float4 vb = *(const float4*)&vrow[k + 4];
        bf16x8 xf = pack8(xa, xb);
        bf16x8 vf = pack8(va, vb);
        *(bf16x8*)&Xb[(size_t)(tok0 + lr) * D_ + k] = xf;
        acc = __builtin_amdgcn_mfma_f32_16x16x32_bf16(xf, vf, acc, 0, 0, 0);
    }
#pragma unroll
    for (int rr = 0; rr < 4; rr++)
        Z[(size_t)(tok0 + lq * 4 + rr) * R_ + lr] = acc[rr];
}

__global__ void zero_f32(float* __restrict__ p, int n) {
    int i = blockIdx.x * 256 + threadIdx.x;
    if (i < n) p[i] = 0.f;
}

// ---------------------------------------------------------------------------
// Scan with on-the-fly lam/bu recompute; alpha finalized inline
// (alpha = sigmoid(al_acc + E2b[c])).
// ---------------------------------------------------------------------------
__device__ __forceinline__ void load_chunk_lds(const float* __restrict__ Z,
                                               const float* __restrict__ al_acc,
                                               const float* __restrict__ E2b,
                                               int tok0, int t,
                                               float* Zs, float* als) {
#pragma unroll
    for (int i = t; i < L_ * R_ / 4; i += 192)
        *(float4*)&Zs[i * 4] = *(const float4*)&Z[(size_t)tok0 * R_ + i * 4];
    als[t] = sigmoidf_(al_acc[(size_t)tok0 * 3 + t] + E2b[t % 3]);   // 192 = 64*3
}

__device__ __forceinline__ float dot16(const float* zrow, const float4* u) {
    float4 z0 = *(const float4*)&zrow[0],  z1 = *(const float4*)&zrow[4];
    float4 z2 = *(const float4*)&zrow[8],  z3 = *(const float4*)&zrow[12];
    return z0.x*u[0].x + z0.y*u[0].y + z0.z*u[0].z + z0.w*u[0].w
         + z1.x*u[1].x + z1.y*u[1].y + z1.z*u[1].z + z1.w*u[1].w
         + z2.x*u[2].x + z2.y*u[2].y + z2.z*u[2].z + z2.w*u[2].w
         + z3.x*u[3].x + z3.y*u[3].y + z3.z*u[3].z + z3.w*u[3].w;
}

__global__ __launch_bounds__(192)
void scan_pass1(const float* __restrict__ Z, const float* __restrict__ al_acc,
                const float* __restrict__ E2b,
                const float* __restrict__ Uw, const float* __restrict__ a_base,
                const float* __restrict__ tanhd,
                float* __restrict__ Aagg, float* __restrict__ Send) {
    __shared__ float Zs[L_ * R_];
    __shared__ float als[L_ * 3];
    const int t = threadIdx.x;
    const int c = blockIdx.x & (NC_ - 1);
    const int b = blockIdx.x >> 6;
    const int tok0 = b * T_ + c * L_;
    const int d0 = t * 4;
    const int buck = d0 >> 8;
    load_chunk_lds(Z, al_acc, E2b, tok0, t, Zs, als);

    float4 u[4][4];
#pragma unroll
    for (int j = 0; j < 4; j++)
#pragma unroll
        for (int q = 0; q < 4; q++)
            u[j][q] = *(const float4*)&Uw[(size_t)(d0 + j) * R_ + q * 4];
    float4 ab = *(const float4*)&a_base[d0];
    float4 td = *(const float4*)&tanhd[d0];
    float abv[4] = {ab.x, ab.y, ab.z, ab.w};
    float tdv[4] = {td.x, td.y, td.z, td.w};
    __syncthreads();

    float a[4] = {1.f, 1.f, 1.f, 1.f}, s[4] = {};
    for (int i = 0; i < L_; i++) {
        float av = als[i * 3 + buck];
#pragma unroll
        for (int j = 0; j < 4; j++) {
            float lam = sigmoidf_(fmaf(av, tdv[j], abv[j]));
            float bu  = dot16(&Zs[i * R_], u[j]);
            a[j] *= lam;
            s[j] = fmaf(lam, s[j], bu);
        }
    }
    size_t o = ((size_t)(b * NC_ + c)) * D_ + d0;
    *(float4*)&Aagg[o] = make_float4(a[0], a[1], a[2], a[3]);
    *(float4*)&Send[o] = make_float4(s[0], s[1], s[2], s[3]);
}

__global__ void scan_pass2(const float* __restrict__ Aagg, const float* __restrict__ Send,
                           float* __restrict__ Cin) {
    const int d = threadIdx.x;              // 768 threads
    const int b = blockIdx.x;               // 8 blocks
    float s = 0.f;
    for (int c = 0; c < NC_; c++) {
        size_t o = ((size_t)(b * NC_ + c)) * D_ + d;
        Cin[o] = s;
        s = fmaf(Aagg[o], s, Send[o]);
    }
}

__global__ __launch_bounds__(192)
void scan_pass3(const float* __restrict__ Z, const float* __restrict__ al_acc,
                const float* __restrict__ E2b,
                const float* __restrict__ Uw, const float* __restrict__ a_base,
                const float* __restrict__ tanhd, const float* __restrict__ Cin,
                unsigned short* __restrict__ Sout) {
    __shared__ float Zs[L_ * R_];
    __shared__ float als[L_ * 3];
    const int t = threadIdx.x;
    const int c = blockIdx.x & (NC_ - 1);
    const int b = blockIdx.x >> 6;
    const int tok0 = b * T_ + c * L_;
    const int d0 = t * 4;
    const int buck = d0 >> 8;
    load_chunk_lds(Z, al_acc, E2b, tok0, t, Zs, als);

    float4 u[4][4];
#pragma unroll
    for (int j = 0; j < 4; j++)
#pragma unroll
        for (int q = 0; q < 4; q++)
            u[j][q] = *(const float4*)&Uw[(size_t)(d0 + j) * R_ + q * 4];
    float4 ab = *(const float4*)&a_base[d0];
    float4 td = *(const float4*)&tanhd[d0];
    float abv[4] = {ab.x, ab.y, ab.z, ab.w};
    float tdv[4] = {td.x, td.y, td.z, td.w};
    __syncthreads();

    size_t ci = ((size_t)(b * NC_ + c)) * D_ + d0;
    float4 c4 = *(const float4*)&Cin[ci];
    float s[4] = {c4.x, c4.y, c4.z, c4.w};
    for (int i = 0; i < L_; i++) {
        float av = als[i * 3 + buck];
#pragma unroll
        for (int j = 0; j < 4; j++) {
            float lam = sigmoidf_(fmaf(av, tdv[j], abv[j]));
            float bu  = dot16(&Zs[i * R_], u[j]);
            s[j] = fmaf(lam, s[j], bu);
        }
        *(ushort4*)&Sout[(size_t)(tok0 + i) * D_ + d0] =
            make_ushort4(f2bf(s[0]), f2bf(s[1]), f2bf(s[2]), f2bf(s[3]));
    }
}

// ---------------------------------------------------------------------------
// small conversion kernels
// ---------------------------------------------------------------------------
__global__ void cvt_bf16_vec(const float* __restrict__ in, unsigned short* __restrict__ out, int n4) {
    int i = blockIdx.x * 256 + threadIdx.x;
    if (i < n4) {
        float4 v = ((const float4*)in)[i];
        ((ushort4*)out)[i] = make_ushort4(f2bf(v.x), f2bf(v.y), f2bf(v.z), f2bf(v.w));
    }
}
__global__ void tanh_vec(const float* __restrict__ in, float* __restrict__ out, int n) {
    int i = blockIdx.x * 256 + threadIdx.x;
    if (i < n) out[i] = tanhf(in[i]);
}

// ---------------------------------------------------------------------------
extern "C" void kernel_launch(void* const* d_in, const int* in_sizes, int n_in,
                              void* d_out, int out_size, void* d_ws, size_t ws_size,
                              hipStream_t stream) {
    const float* x       = (const float*)d_in[0];
    const float* V_w     = (const float*)d_in[1];
    const float* U_w     = (const float*)d_in[2];
    const float* E1_w    = (const float*)d_in[3];
    const float* E1_b    = (const float*)d_in[4];
    const float* E2_w    = (const float*)d_in[5];
    const float* E2_b    = (const float*)d_in[6];
    const float* a_base  = (const float*)d_in[7];
    const float* a_delta = (const float*)d_in[8];
    const float* C_w     = (const float*)d_in[9];
    const float* G_w     = (const float*)d_in[10];
    const float* G_b     = (const float*)d_in[11];
    float* out = (float*)d_out;

    // workspace layout
    char* p = (char*)d_ws;
    float* Aagg   = (float*)p;          p += (size_t)B_ * NC_ * D_ * 4;
    float* Send   = (float*)p;          p += (size_t)B_ * NC_ * D_ * 4;
    float* Cin    = (float*)p;          p += (size_t)B_ * NC_ * D_ * 4;
    float* tanhd  = (float*)p;          p += (size_t)D_ * 4;
    float* Z      = (float*)p;          p += (size_t)N_ * R_ * 4;
    float* al_acc = (float*)p;          p += (size_t)N_ * 3 * 4;
    unsigned short* x_bf  = (unsigned short*)p; p += (size_t)N_ * D_ * 2;
    unsigned short* S_bf  = (unsigned short*)p; p += (size_t)N_ * D_ * 2;
    unsigned short* E1_bf = (unsigned short*)p; p += (size_t)DB_ * D_ * 2;
    unsigned short* Cw_bf = (unsigned short*)p; p += (size_t)D_ * D_ * 2;
    unsigned short* Gw_bf = (unsigned short*)p; p += (size_t)D_ * D_ * 2;

    // weight conversions + small precompute + alpha accumulator zero
    {
        int n4 = DB_ * D_ / 4;
        cvt_bf16_vec<<<(n4 + 255) / 256, 256, 0, stream>>>(E1_w, E1_bf, n4);
        n4 = D_ * D_ / 4;
        cvt_bf16_vec<<<(n4 + 255) / 256, 256, 0, stream>>>(C_w, Cw_bf, n4);
        cvt_bf16_vec<<<(n4 + 255) / 256, 256, 0, stream>>>(G_w, Gw_bf, n4);
        tanh_vec<<<3, 256, 0, stream>>>(a_delta, tanhd, D_);
        zero_f32<<<(N_ * 3 + 255) / 256, 256, 0, stream>>>(al_acc, N_ * 3);
    }

    // x -> bf16 and Z = x@V^T in one pass
    cvtz_kernel<<<N_ / 64, 256, 0, stream>>>(x, V_w, x_bf, Z);

    // E1 GEMM with fused alpha partials (H never materialized)
    gemm_e1_alpha<<<512, 256, 0, stream>>>(x_bf, E1_bf, E1_b, E2_w, al_acc);

    scan_pass1<<<B_ * NC_, 192, 0, stream>>>(Z, al_acc, E2_b, U_w, a_base, tanhd, Aagg, Send);
    scan_pass2<<<B_,       D_,  0, stream>>>(Aagg, Send, Cin);
    scan_pass3<<<B_ * NC_, 192, 0, stream>>>(Z, al_acc, E2_b, U_w, a_base, tanhd, Cin, S_bf);

    gemm_fused_out<<<768, 256, 0, stream>>>(x_bf, Gw_bf, S_bf, Cw_bf, G_b, out);
}

// Round 9
// 363.608 us; speedup vs baseline: 1.1114x; 1.1114x over previous
//
#include <hip/hip_runtime.h>
#include <hip/hip_bf16.h>
#include <math.h>

// Problem constants
#define B_   8
#define T_   4096
#define D_   768
#define R_   16
#define DB_  256
#define N_   (B_ * T_)      // 32768 tokens
#define NC_  64             // scan chunks per sequence
#define L_   (T_ / NC_)     // 64 steps per chunk
#define NKS_ (D_ / 32)      // 24 K-steps of 32
#define BUF_  12288         // e1 kernel buffer: A 256x32 + B 128x32 (elems)
#define BUF2_ 16384         // fused kernel buffer: A 256x32 + B 256x32 (elems)

typedef __attribute__((ext_vector_type(8))) short bf16x8;
typedef __attribute__((ext_vector_type(4))) float f32x4;

__device__ __forceinline__ float gelu_exact(float x) {
    return 0.5f * x * (1.0f + erff(x * 0.70710678118654752f));
}
__device__ __forceinline__ float sigmoidf_(float x) {
    return 1.0f / (1.0f + expf(-x));
}
__device__ __forceinline__ float bf2f(unsigned short u) {
    return __uint_as_float(((unsigned)u) << 16);
}
__device__ __forceinline__ unsigned short f2bf(float f) {
    __hip_bfloat16 h = __float2bfloat16(f);   // RNE
    return *(unsigned short*)&h;
}
__device__ __forceinline__ bf16x8 pack8(float4 a, float4 b) {
    bf16x8 r;
    r[0] = (short)f2bf(a.x); r[1] = (short)f2bf(a.y);
    r[2] = (short)f2bf(a.z); r[3] = (short)f2bf(a.w);
    r[4] = (short)f2bf(b.x); r[5] = (short)f2bf(b.y);
    r[6] = (short)f2bf(b.z); r[7] = (short)f2bf(b.w);
    return r;
}

// async global->LDS, 16B per lane. LDS dest = wave-uniform base + lane*16.
__device__ __forceinline__ void gload16(const unsigned short* g, unsigned short* l) {
    __builtin_amdgcn_global_load_lds(
        (const __attribute__((address_space(1))) unsigned int*)(const void*)g,
        (__attribute__((address_space(3))) unsigned int*)(void*)l,
        16, 0, 0);
}

// swizzled LDS fragment read: 8 bf16 for mfma_16x16x32 (bank-conflict-free;
// source quad was pre-swizzled with the same q ^= (row>>1)&3 — rule 21)
__device__ __forceinline__ bf16x8 frag_read(const unsigned short* lds, int row, int lq) {
    int q = lq ^ ((row >> 1) & 3);
    return *(const bf16x8*)(lds + row * 32 + q * 8);
}

// chunked XCD swizzle (nwg % 8 == 0), then col-fastest decode
__device__ __forceinline__ void tile_decode(int nwg, int ncol, int& rowt, int& colt) {
    int bid = blockIdx.x;
    int cpx = nwg >> 3;
    int swz = (bid & 7) * cpx + (bid >> 3);
    colt = swz % ncol;
    rowt = swz / ncol;
}

// ===========================================================================
// Variant 1 (R7-proven): 512 threads, block 256x128, wave tile 64x64.
// Used by gemm_e1_alpha. Loads/thread/K-step = 3; vmcnt(3).
// ===========================================================================
__device__ __forceinline__ void stage_a(const unsigned short* src, int row0, int k0,
                                        unsigned short* lds, int w, int l) {
#pragma unroll
    for (int j = 0; j < 2; ++j) {
        int i = ((w * 2 + j) << 6) + l;     // 0..1023
        int row = i >> 2, q = i & 3;
        int qs = q ^ ((row >> 1) & 3);
        gload16(src + (size_t)(row0 + row) * D_ + k0 + qs * 8, lds + ((w * 2 + j) << 9));
    }
}
__device__ __forceinline__ void stage_b(const unsigned short* src, int col0, int k0,
                                        unsigned short* lds, int w, int l) {
    int i = (w << 6) + l;                   // 0..511
    int row = i >> 2, q = i & 3;
    int qs = q ^ ((row >> 1) & 3);
    gload16(src + (size_t)(col0 + row) * D_ + k0 + qs * 8, lds + (w << 9));
}

__device__ __forceinline__ void tile_mfma44(const unsigned short* la, const unsigned short* lb,
                                            int wrow, int wcol, int lr, int lq,
                                            f32x4 acc[4][4]) {
    bf16x8 a[4], b[4];
#pragma unroll
    for (int m = 0; m < 4; m++) a[m] = frag_read(la, wrow + m * 16 + lr, lq);
#pragma unroll
    for (int n = 0; n < 4; n++) b[n] = frag_read(lb, wcol + n * 16 + lr, lq);
    __builtin_amdgcn_s_setprio(1);
#pragma unroll
    for (int m = 0; m < 4; m++)
#pragma unroll
        for (int n = 0; n < 4; n++)
            acc[m][n] = __builtin_amdgcn_mfma_f32_16x16x32_bf16(a[m], b[n], acc[m][n], 0, 0, 0);
    __builtin_amdgcn_s_setprio(0);
}

__device__ __forceinline__ void kloop3_128(const unsigned short* __restrict__ A,
                                           const unsigned short* __restrict__ Bm,
                                           int row0, int col0,
                                           unsigned short* lds,   // 3 * BUF_
                                           int w, int l, f32x4 acc[4][4]) {
    const int lr = l & 15, lq = l >> 4;
    const int wrow = (w >> 1) * 64, wcol = (w & 1) * 64;

    stage_a(A,  row0, 0,  lds,                w, l);
    stage_b(Bm, col0, 0,  lds + 8192,         w, l);
    stage_a(A,  row0, 32, lds + BUF_,         w, l);
    stage_b(Bm, col0, 32, lds + BUF_ + 8192,  w, l);

#pragma unroll 3
    for (int t = 0; t < NKS_ - 2; ++t) {
        asm volatile("s_waitcnt vmcnt(3)" ::: "memory");
        __builtin_amdgcn_s_barrier();
        __builtin_amdgcn_sched_barrier(0);
        unsigned short* bn = lds + ((t + 2) % 3) * BUF_;
        stage_a(A,  row0, (t + 2) * 32, bn,        w, l);
        stage_b(Bm, col0, (t + 2) * 32, bn + 8192, w, l);
        unsigned short* bc = lds + (t % 3) * BUF_;
        tile_mfma44(bc, bc + 8192, wrow, wcol, lr, lq, acc);
    }
    asm volatile("s_waitcnt vmcnt(3)" ::: "memory");
    __builtin_amdgcn_s_barrier();
    __builtin_amdgcn_sched_barrier(0);
    {
        unsigned short* bc = lds + ((NKS_ - 2) % 3) * BUF_;
        tile_mfma44(bc, bc + 8192, wrow, wcol, lr, lq, acc);
    }
    asm volatile("s_waitcnt vmcnt(0)" ::: "memory");
    __builtin_amdgcn_s_barrier();
    __builtin_amdgcn_sched_barrier(0);
    {
        unsigned short* bc = lds + ((NKS_ - 1) % 3) * BUF_;
        tile_mfma44(bc, bc + 8192, wrow, wcol, lr, lq, acc);
    }
}

// ===========================================================================
// Variant 2 (new): 512 threads, block 256x256, wave grid 2x4, wave tile
// 128x64 (m201 geometry). LDS 3 x 32KB = 96KB -> 1 block/CU.
// Loads/thread/K-step = 4; 2 tiles in flight; vmcnt(4).
// ===========================================================================
__device__ __forceinline__ void stage_ab256(const unsigned short* __restrict__ A,
                                            const unsigned short* __restrict__ Bm,
                                            int row0, int col0, int k0,
                                            unsigned short* buf, int w, int l) {
#pragma unroll
    for (int j = 0; j < 2; ++j) {               // A: 256x32 = 1024 chunks
        int i = ((w * 2 + j) << 6) + l;
        int row = i >> 2, q = i & 3;
        int qs = q ^ ((row >> 1) & 3);
        gload16(A + (size_t)(row0 + row) * D_ + k0 + qs * 8, buf + ((w * 2 + j) << 9));
    }
    unsigned short* bl = buf + 8192;
#pragma unroll
    for (int j = 0; j < 2; ++j) {               // B: 256x32 = 1024 chunks
        int i = ((w * 2 + j) << 6) + l;
        int row = i >> 2, q = i & 3;
        int qs = q ^ ((row >> 1) & 3);
        gload16(Bm + (size_t)(col0 + row) * D_ + k0 + qs * 8, bl + ((w * 2 + j) << 9));
    }
}

__device__ __forceinline__ void tile_mfma84(const unsigned short* buf,
                                            int wrow, int wcol, int lr, int lq,
                                            f32x4 acc[8][4]) {
    const unsigned short* la = buf;
    const unsigned short* lb = buf + 8192;
    bf16x8 b[4];
#pragma unroll
    for (int n = 0; n < 4; n++) b[n] = frag_read(lb, wcol + n * 16 + lr, lq);
    __builtin_amdgcn_s_setprio(1);
#pragma unroll
    for (int m = 0; m < 8; m++) {
        bf16x8 a = frag_read(la, wrow + m * 16 + lr, lq);
#pragma unroll
        for (int n = 0; n < 4; n++)
            acc[m][n] = __builtin_amdgcn_mfma_f32_16x16x32_bf16(a, b[n], acc[m][n], 0, 0, 0);
    }
    __builtin_amdgcn_s_setprio(0);
}

__device__ __forceinline__ void prologue256(const unsigned short* __restrict__ A,
                                            const unsigned short* __restrict__ Bm,
                                            int row0, int col0,
                                            unsigned short* lds, int w, int l) {
    stage_ab256(A, Bm, row0, col0, 0,  lds,         w, l);
    stage_ab256(A, Bm, row0, col0, 32, lds + BUF2_, w, l);
}

template <bool DO_PROLOGUE>
__device__ __forceinline__ void kloop3_256(const unsigned short* __restrict__ A,
                                           const unsigned short* __restrict__ Bm,
                                           int row0, int col0,
                                           unsigned short* lds,   // 3 * BUF2_
                                           int w, int l, f32x4 acc[8][4]) {
    const int lr = l & 15, lq = l >> 4;
    const int wrow = (w >> 2) * 128, wcol = (w & 3) * 64;

    if (DO_PROLOGUE) prologue256(A, Bm, row0, col0, lds, w, l);

#pragma unroll 3
    for (int t = 0; t < NKS_ - 2; ++t) {
        asm volatile("s_waitcnt vmcnt(4)" ::: "memory");
        __builtin_amdgcn_s_barrier();
        __builtin_amdgcn_sched_barrier(0);
        stage_ab256(A, Bm, row0, col0, (t + 2) * 32, lds + ((t + 2) % 3) * BUF2_, w, l);
        tile_mfma84(lds + (t % 3) * BUF2_, wrow, wcol, lr, lq, acc);
    }
    asm volatile("s_waitcnt vmcnt(4)" ::: "memory");
    __builtin_amdgcn_s_barrier();
    __builtin_amdgcn_sched_barrier(0);
    tile_mfma84(lds + ((NKS_ - 2) % 3) * BUF2_, wrow, wcol, lr, lq, acc);
    asm volatile("s_waitcnt vmcnt(0)" ::: "memory");
    __builtin_amdgcn_s_barrier();
    __builtin_amdgcn_sched_barrier(0);
    tile_mfma84(lds + ((NKS_ - 1) % 3) * BUF2_, wrow, wcol, lr, lq, acc);
}

// ---------------------------------------------------------------------------
// E1 GEMM + alpha partials (R7-proven shape). Block 256x128, 512 thr,
// grid 256 (2 col x 128 row). H never materialized.
// ---------------------------------------------------------------------------
__global__ __launch_bounds__(512, 2)
void gemm_e1_alpha(const unsigned short* __restrict__ Xb,
                   const unsigned short* __restrict__ Wb,
                   const float* __restrict__ bias,
                   const float* __restrict__ E2w,
                   float* __restrict__ alpha_acc) {
    __shared__ unsigned short lds[3 * BUF_];
    const int t = threadIdx.x, l = t & 63, w = t >> 6;
    int rowt, colt;
    tile_decode(256, 2, rowt, colt);
    const int row0 = rowt * 256, col0 = colt * 128;
    const int lr = l & 15, lq = l >> 4;
    const int wrow = (w >> 1) * 64, wcol = (w & 1) * 64;
    f32x4 acc[4][4] = {};
    kloop3_128(Xb, Wb, row0, col0, lds, w, l, acc);

    float bia[4], e2v[3][4];
#pragma unroll
    for (int n = 0; n < 4; n++) {
        int col = col0 + wcol + n * 16 + lr;
        bia[n] = bias[col];
#pragma unroll
        for (int c = 0; c < 3; c++) e2v[c][n] = E2w[c * DB_ + col];
    }
#pragma unroll
    for (int m = 0; m < 4; m++)
#pragma unroll
        for (int r = 0; r < 4; r++) {
            float p0 = 0.f, p1 = 0.f, p2 = 0.f;
#pragma unroll
            for (int n = 0; n < 4; n++) {
                float h = gelu_exact(acc[m][n][r] + bia[n]);
                p0 = fmaf(h, e2v[0][n], p0);
                p1 = fmaf(h, e2v[1][n], p1);
                p2 = fmaf(h, e2v[2][n], p2);
            }
#pragma unroll
            for (int s = 1; s < 16; s <<= 1) {
                p0 += __shfl_xor(p0, s);
                p1 += __shfl_xor(p1, s);
                p2 += __shfl_xor(p2, s);
            }
            if (lr == 0) {
                int row = row0 + wrow + m * 16 + lq * 4 + r;
                atomicAdd(&alpha_acc[(size_t)row * 3 + 0], p0);
                atomicAdd(&alpha_acc[(size_t)row * 3 + 1], p1);
                atomicAdd(&alpha_acc[(size_t)row * 3 + 2], p2);
            }
        }
}

// ---------------------------------------------------------------------------
// Fused: gate = sigmoid(Xb@G^T+Gb) (packed bf16 in regs), then
//        out = x_bf + gelu(Sb@C^T) * gate.
// Block 256x256, 512 thr, grid 384 (3 col x 128 row), 1 block/CU.
// ---------------------------------------------------------------------------
__global__ __launch_bounds__(512, 1)
void gemm_fused_out(const unsigned short* __restrict__ Xb,
                    const unsigned short* __restrict__ Gwb,
                    const unsigned short* __restrict__ Sb,
                    const unsigned short* __restrict__ Cwb,
                    const float* __restrict__ Gbias,
                    float* __restrict__ out) {
    __shared__ unsigned short lds[3 * BUF2_];
    const int t = threadIdx.x, l = t & 63, w = t >> 6;
    int rowt, colt;
    tile_decode(384, 3, rowt, colt);
    const int row0 = rowt * 256, col0 = colt * 256;
    const int lr = l & 15, lq = l >> 4;
    const int wrow = (w >> 2) * 128, wcol = (w & 3) * 64;

    // hoist Gbias so the gate pack is pure VALU (vmcnt stream stays clean)
    float gb[4];
#pragma unroll
    for (int n = 0; n < 4; n++) gb[n] = Gbias[col0 + wcol + n * 16 + lr];

    f32x4 acc[8][4] = {};
    kloop3_256<true>(Xb, Gwb, row0, col0, lds, w, l, acc);

    // issue kloop-C prologue now: HBM latency hides under the gate pack.
    // Safe: buffers 0/1's readers all passed the final kloop-G barriers.
    prologue256(Sb, Cwb, row0, col0, lds, w, l);

    unsigned int gp[8][4][2];
#pragma unroll
    for (int m = 0; m < 8; m++)
#pragma unroll
        for (int n = 0; n < 4; n++) {
            gp[m][n][0] = (unsigned)f2bf(sigmoidf_(acc[m][n][0] + gb[n]))
                        | ((unsigned)f2bf(sigmoidf_(acc[m][n][1] + gb[n])) << 16);
            gp[m][n][1] = (unsigned)f2bf(sigmoidf_(acc[m][n][2] + gb[n]))
                        | ((unsigned)f2bf(sigmoidf_(acc[m][n][3] + gb[n])) << 16);
            acc[m][n] = (f32x4){0.f, 0.f, 0.f, 0.f};
        }

    kloop3_256<false>(Sb, Cwb, row0, col0, lds, w, l, acc);

#pragma unroll
    for (int m = 0; m < 8; m++)
#pragma unroll
        for (int n = 0; n < 4; n++) {
            int col = col0 + wcol + n * 16 + lr;
#pragma unroll
            for (int r = 0; r < 4; r++) {
                int row = row0 + wrow + m * 16 + lq * 4 + r;
                size_t o = (size_t)row * D_ + col;
                float g = bf2f((unsigned short)(gp[m][n][r >> 1] >> ((r & 1) * 16)));
                out[o] = bf2f(Xb[o]) + gelu_exact(acc[m][n][r]) * g;
            }
        }
}

// ---------------------------------------------------------------------------
// Fused cvt + Z: x_bf = bf16(x);  Z = x_bf @ V^T (V converted on the fly).
// ---------------------------------------------------------------------------
__global__ __launch_bounds__(256)
void cvtz_kernel(const float* __restrict__ X, const float* __restrict__ Vw,
                 unsigned short* __restrict__ Xb, float* __restrict__ Z) {
    const int t = threadIdx.x, l = t & 63, w = t >> 6;
    const int lr = l & 15, lq = l >> 4;
    const int tok0 = (blockIdx.x * 4 + w) * 16;
    const float* xrow = X  + (size_t)(tok0 + lr) * D_;
    const float* vrow = Vw + (size_t)lr * D_;
    f32x4 acc = {};
#pragma unroll 4
    for (int k0 = 0; k0 < D_; k0 += 32) {
        int k = k0 + lq * 8;
        float4 xa = *(const float4*)&xrow[k];
        float4 xb = *(const float4*)&xrow[k + 4];
        float4 va = *(const float4*)&vrow[k];
        float4 vb = *(const float4*)&vrow[k + 4];
        bf16x8 xf = pack8(xa, xb);
        bf16x8 vf = pack8(va, vb);
        *(bf16x8*)&Xb[(size_t)(tok0 + lr) * D_ + k] = xf;
        acc = __builtin_amdgcn_mfma_f32_16x16x32_bf16(xf, vf, acc, 0, 0, 0);
    }
#pragma unroll
    for (int rr = 0; rr < 4; rr++)
        Z[(size_t)(tok0 + lq * 4 + rr) * R_ + lr] = acc[rr];
}

// ---------------------------------------------------------------------------
// Merged setup: cvt E1/C/G to bf16, zero alpha accumulator, tanh(a_delta).
// One kernel, segment-decoded by linear float4 index.
// ---------------------------------------------------------------------------
#define SEG_E1  (DB_ * D_ / 4)             // 49152
#define SEG_W   (D_ * D_ / 4)              // 147456
#define SEG_Z   (N_ * 3 / 4)               // 24576
#define SEG_TOT (SEG_E1 + 2 * SEG_W + SEG_Z + 192)

__global__ void setup_all(const float* __restrict__ E1_w, const float* __restrict__ C_w,
                          const float* __restrict__ G_w, const float* __restrict__ a_delta,
                          unsigned short* __restrict__ E1b, unsigned short* __restrict__ Cwb,
                          unsigned short* __restrict__ Gwb, float* __restrict__ al_acc,
                          float* __restrict__ tanhd) {
    int i = blockIdx.x * 256 + threadIdx.x;
    if (i < SEG_E1) {
        float4 v = ((const float4*)E1_w)[i];
        ((ushort4*)E1b)[i] = make_ushort4(f2bf(v.x), f2bf(v.y), f2bf(v.z), f2bf(v.w));
    } else if (i < SEG_E1 + SEG_W) {
        int j = i - SEG_E1;
        float4 v = ((const float4*)C_w)[j];
        ((ushort4*)Cwb)[j] = make_ushort4(f2bf(v.x), f2bf(v.y), f2bf(v.z), f2bf(v.w));
    } else if (i < SEG_E1 + 2 * SEG_W) {
        int j = i - SEG_E1 - SEG_W;
        float4 v = ((const float4*)G_w)[j];
        ((ushort4*)Gwb)[j] = make_ushort4(f2bf(v.x), f2bf(v.y), f2bf(v.z), f2bf(v.w));
    } else if (i < SEG_E1 + 2 * SEG_W + SEG_Z) {
        int j = i - SEG_E1 - 2 * SEG_W;
        ((float4*)al_acc)[j] = make_float4(0.f, 0.f, 0.f, 0.f);
    } else if (i < SEG_TOT) {
        int j = (i - SEG_E1 - 2 * SEG_W - SEG_Z) * 4;
        tanhd[j + 0] = tanhf(a_delta[j + 0]);
        tanhd[j + 1] = tanhf(a_delta[j + 1]);
        tanhd[j + 2] = tanhf(a_delta[j + 2]);
        tanhd[j + 3] = tanhf(a_delta[j + 3]);
    }
}

// ---------------------------------------------------------------------------
// Scan with on-the-fly lam/bu recompute; alpha finalized inline.
// ---------------------------------------------------------------------------
__device__ __forceinline__ void load_chunk_lds(const float* __restrict__ Z,
                                               const float* __restrict__ al_acc,
                                               const float* __restrict__ E2b,
                                               int tok0, int t,
                                               float* Zs, float* als) {
#pragma unroll
    for (int i = t; i < L_ * R_ / 4; i += 192)
        *(float4*)&Zs[i * 4] = *(const float4*)&Z[(size_t)tok0 * R_ + i * 4];
    als[t] = sigmoidf_(al_acc[(size_t)tok0 * 3 + t] + E2b[t % 3]);   // 192 = 64*3
}

__device__ __forceinline__ float dot16(const float* zrow, const float4* u) {
    float4 z0 = *(const float4*)&zrow[0],  z1 = *(const float4*)&zrow[4];
    float4 z2 = *(const float4*)&zrow[8],  z3 = *(const float4*)&zrow[12];
    return z0.x*u[0].x + z0.y*u[0].y + z0.z*u[0].z + z0.w*u[0].w
         + z1.x*u[1].x + z1.y*u[1].y + z1.z*u[1].z + z1.w*u[1].w
         + z2.x*u[2].x + z2.y*u[2].y + z2.z*u[2].z + z2.w*u[2].w
         + z3.x*u[3].x + z3.y*u[3].y + z3.z*u[3].z + z3.w*u[3].w;
}

__global__ __launch_bounds__(192)
void scan_pass1(const float* __restrict__ Z, const float* __restrict__ al_acc,
                const float* __restrict__ E2b,
                const float* __restrict__ Uw, const float* __restrict__ a_base,
                const float* __restrict__ tanhd,
                float* __restrict__ Aagg, float* __restrict__ Send) {
    __shared__ float Zs[L_ * R_];
    __shared__ float als[L_ * 3];
    const int t = threadIdx.x;
    const int c = blockIdx.x & (NC_ - 1);
    const int b = blockIdx.x >> 6;
    const int tok0 = b * T_ + c * L_;
    const int d0 = t * 4;
    const int buck = d0 >> 8;
    load_chunk_lds(Z, al_acc, E2b, tok0, t, Zs, als);

    float4 u[4][4];
#pragma unroll
    for (int j = 0; j < 4; j++)
#pragma unroll
        for (int q = 0; q < 4; q++)
            u[j][q] = *(const float4*)&Uw[(size_t)(d0 + j) * R_ + q * 4];
    float4 ab = *(const float4*)&a_base[d0];
    float4 td = *(const float4*)&tanhd[d0];
    float abv[4] = {ab.x, ab.y, ab.z, ab.w};
    float tdv[4] = {td.x, td.y, td.z, td.w};
    __syncthreads();

    float a[4] = {1.f, 1.f, 1.f, 1.f}, s[4] = {};
    for (int i = 0; i < L_; i++) {
        float av = als[i * 3 + buck];
#pragma unroll
        for (int j = 0; j < 4; j++) {
            float lam = sigmoidf_(fmaf(av, tdv[j], abv[j]));
            float bu  = dot16(&Zs[i * R_], u[j]);
            a[j] *= lam;
            s[j] = fmaf(lam, s[j], bu);
        }
    }
    size_t o = ((size_t)(b * NC_ + c)) * D_ + d0;
    *(float4*)&Aagg[o] = make_float4(a[0], a[1], a[2], a[3]);
    *(float4*)&Send[o] = make_float4(s[0], s[1], s[2], s[3]);
}

__global__ void scan_pass2(const float* __restrict__ Aagg, const float* __restrict__ Send,
                           float* __restrict__ Cin) {
    const int d = threadIdx.x;              // 768 threads
    const int b = blockIdx.x;               // 8 blocks
    float s = 0.f;
    for (int c = 0; c < NC_; c++) {
        size_t o = ((size_t)(b * NC_ + c)) * D_ + d;
        Cin[o] = s;
        s = fmaf(Aagg[o], s, Send[o]);
    }
}

__global__ __launch_bounds__(192)
void scan_pass3(const float* __restrict__ Z, const float* __restrict__ al_acc,
                const float* __restrict__ E2b,
                const float* __restrict__ Uw, const float* __restrict__ a_base,
                const float* __restrict__ tanhd, const float* __restrict__ Cin,
                unsigned short* __restrict__ Sout) {
    __shared__ float Zs[L_ * R_];
    __shared__ float als[L_ * 3];
    const int t = threadIdx.x;
    const int c = blockIdx.x & (NC_ - 1);
    const int b = blockIdx.x >> 6;
    const int tok0 = b * T_ + c * L_;
    const int d0 = t * 4;
    const int buck = d0 >> 8;
    load_chunk_lds(Z, al_acc, E2b, tok0, t, Zs, als);

    float4 u[4][4];
#pragma unroll
    for (int j = 0; j < 4; j++)
#pragma unroll
        for (int q = 0; q < 4; q++)
            u[j][q] = *(const float4*)&Uw[(size_t)(d0 + j) * R_ + q * 4];
    float4 ab = *(const float4*)&a_base[d0];
    float4 td = *(const float4*)&tanhd[d0];
    float abv[4] = {ab.x, ab.y, ab.z, ab.w};
    float tdv[4] = {td.x, td.y, td.z, td.w};
    __syncthreads();

    size_t ci = ((size_t)(b * NC_ + c)) * D_ + d0;
    float4 c4 = *(const float4*)&Cin[ci];
    float s[4] = {c4.x, c4.y, c4.z, c4.w};
    for (int i = 0; i < L_; i++) {
        float av = als[i * 3 + buck];
#pragma unroll
        for (int j = 0; j < 4; j++) {
            float lam = sigmoidf_(fmaf(av, tdv[j], abv[j]));
            float bu  = dot16(&Zs[i * R_], u[j]);
            s[j] = fmaf(lam, s[j], bu);
        }
        *(ushort4*)&Sout[(size_t)(tok0 + i) * D_ + d0] =
            make_ushort4(f2bf(s[0]), f2bf(s[1]), f2bf(s[2]), f2bf(s[3]));
    }
}

// ---------------------------------------------------------------------------
extern "C" void kernel_launch(void* const* d_in, const int* in_sizes, int n_in,
                              void* d_out, int out_size, void* d_ws, size_t ws_size,
                              hipStream_t stream) {
    const float* x       = (const float*)d_in[0];
    const float* V_w     = (const float*)d_in[1];
    const float* U_w     = (const float*)d_in[2];
    const float* E1_w    = (const float*)d_in[3];
    const float* E1_b    = (const float*)d_in[4];
    const float* E2_w    = (const float*)d_in[5];
    const float* E2_b    = (const float*)d_in[6];
    const float* a_base  = (const float*)d_in[7];
    const float* a_delta = (const float*)d_in[8];
    const float* C_w     = (const float*)d_in[9];
    const float* G_w     = (const float*)d_in[10];
    const float* G_b     = (const float*)d_in[11];
    float* out = (float*)d_out;

    // workspace layout
    char* p = (char*)d_ws;
    float* Aagg   = (float*)p;          p += (size_t)B_ * NC_ * D_ * 4;
    float* Send   = (float*)p;          p += (size_t)B_ * NC_ * D_ * 4;
    float* Cin    = (float*)p;          p += (size_t)B_ * NC_ * D_ * 4;
    float* tanhd  = (float*)p;          p += (size_t)D_ * 4;
    float* Z      = (float*)p;          p += (size_t)N_ * R_ * 4;
    float* al_acc = (float*)p;          p += (size_t)N_ * 3 * 4;
    unsigned short* x_bf  = (unsigned short*)p; p += (size_t)N_ * D_ * 2;
    unsigned short* S_bf  = (unsigned short*)p; p += (size_t)N_ * D_ * 2;
    unsigned short* E1_bf = (unsigned short*)p; p += (size_t)DB_ * D_ * 2;
    unsigned short* Cw_bf = (unsigned short*)p; p += (size_t)D_ * D_ * 2;
    unsigned short* Gw_bf = (unsigned short*)p; p += (size_t)D_ * D_ * 2;

    // merged setup (weights cvt + zero + tanh) — one launch
    setup_all<<<(SEG_TOT + 255) / 256, 256, 0, stream>>>(
        E1_w, C_w, G_w, a_delta, E1_bf, Cw_bf, Gw_bf, al_acc, tanhd);

    // x -> bf16 and Z = x@V^T in one pass
    cvtz_kernel<<<N_ / 64, 256, 0, stream>>>(x, V_w, x_bf, Z);

    // E1 GEMM with fused alpha partials (H never materialized)
    gemm_e1_alpha<<<256, 512, 0, stream>>>(x_bf, E1_bf, E1_b, E2_w, al_acc);

    scan_pass1<<<B_ * NC_, 192, 0, stream>>>(Z, al_acc, E2_b, U_w, a_base, tanhd, Aagg, Send);
    scan_pass2<<<B_,       D_,  0, stream>>>(Aagg, Send, Cin);
    scan_pass3<<<B_ * NC_, 192, 0, stream>>>(Z, al_acc, E2_b, U_w, a_base, tanhd, Cin, S_bf);

    gemm_fused_out<<<384, 512, 0, stream>>>(x_bf, Gw_bf, S_bf, Cw_bf, G_b, out);
}

// Round 10
// 330.112 us; speedup vs baseline: 1.2242x; 1.1015x over previous
//
#include <hip/hip_runtime.h>
#include <hip/hip_bf16.h>
#include <math.h>

// Problem constants
#define B_   8
#define T_   4096
#define D_   768
#define R_   16
#define DB_  256
#define N_   (B_ * T_)      // 32768 tokens
#define NC_  64             // scan chunks per sequence
#define L_   (T_ / NC_)     // 64 steps per chunk
#define NKS_ (D_ / 32)      // 24 K-steps of 32
#define BUF_  12288         // fused buffer: A 256x32 + B 128x32 (elems)
#define BUFE1 8192          // e1 buffer:    A 128x32 + B 128x32 (elems)

typedef __attribute__((ext_vector_type(8))) short bf16x8;
typedef __attribute__((ext_vector_type(4))) float f32x4;

__device__ __forceinline__ float gelu_exact(float x) {
    return 0.5f * x * (1.0f + erff(x * 0.70710678118654752f));
}
__device__ __forceinline__ float sigmoidf_(float x) {
    return 1.0f / (1.0f + expf(-x));
}
__device__ __forceinline__ float bf2f(unsigned short u) {
    return __uint_as_float(((unsigned)u) << 16);
}
__device__ __forceinline__ unsigned short f2bf(float f) {
    __hip_bfloat16 h = __float2bfloat16(f);   // RNE
    return *(unsigned short*)&h;
}
__device__ __forceinline__ bf16x8 pack8(float4 a, float4 b) {
    bf16x8 r;
    r[0] = (short)f2bf(a.x); r[1] = (short)f2bf(a.y);
    r[2] = (short)f2bf(a.z); r[3] = (short)f2bf(a.w);
    r[4] = (short)f2bf(b.x); r[5] = (short)f2bf(b.y);
    r[6] = (short)f2bf(b.z); r[7] = (short)f2bf(b.w);
    return r;
}

// async global->LDS, 16B per lane. LDS dest = wave-uniform base + lane*16.
__device__ __forceinline__ void gload16(const unsigned short* g, unsigned short* l) {
    __builtin_amdgcn_global_load_lds(
        (const __attribute__((address_space(1))) unsigned int*)(const void*)g,
        (__attribute__((address_space(3))) unsigned int*)(void*)l,
        16, 0, 0);
}

// swizzled LDS fragment read: 8 bf16 for mfma_16x16x32 (bank-conflict-free;
// source quad was pre-swizzled with the same q ^= (row>>1)&3 — rule 21)
__device__ __forceinline__ bf16x8 frag_read(const unsigned short* lds, int row, int lq) {
    int q = lq ^ ((row >> 1) & 3);
    return *(const bf16x8*)(lds + row * 32 + q * 8);
}

// chunked XCD swizzle (nwg % 8 == 0), then col-fastest decode
__device__ __forceinline__ void tile_decode(int nwg, int ncol, int& rowt, int& colt) {
    int bid = blockIdx.x;
    int cpx = nwg >> 3;
    int swz = (bid & 7) * cpx + (bid >> 3);
    colt = swz % ncol;
    rowt = swz / ncol;
}

// ===========================================================================
// FUSED-GEMM variant (proven 124.8us): 512 threads, block 256x128,
// wave tile 64x64 (wave grid 4x2). Loads/thread/K-step = 3; vmcnt(3).
// ===========================================================================
__device__ __forceinline__ void stage_a(const unsigned short* src, int row0, int k0,
                                        unsigned short* lds, int w, int l) {
#pragma unroll
    for (int j = 0; j < 2; ++j) {
        int i = ((w * 2 + j) << 6) + l;     // 0..1023 (256 rows x 4 quads)
        int row = i >> 2, q = i & 3;
        int qs = q ^ ((row >> 1) & 3);
        gload16(src + (size_t)(row0 + row) * D_ + k0 + qs * 8, lds + ((w * 2 + j) << 9));
    }
}
__device__ __forceinline__ void stage_b(const unsigned short* src, int col0, int k0,
                                        unsigned short* lds, int w, int l) {
    int i = (w << 6) + l;                   // 0..511 (128 rows x 4 quads)
    int row = i >> 2, q = i & 3;
    int qs = q ^ ((row >> 1) & 3);
    gload16(src + (size_t)(col0 + row) * D_ + k0 + qs * 8, lds + (w << 9));
}

__device__ __forceinline__ void tile_mfma44(const unsigned short* la, const unsigned short* lb,
                                            int wrow, int wcol, int lr, int lq,
                                            f32x4 acc[4][4]) {
    bf16x8 a[4], b[4];
#pragma unroll
    for (int m = 0; m < 4; m++) a[m] = frag_read(la, wrow + m * 16 + lr, lq);
#pragma unroll
    for (int n = 0; n < 4; n++) b[n] = frag_read(lb, wcol + n * 16 + lr, lq);
    __builtin_amdgcn_s_setprio(1);
#pragma unroll
    for (int m = 0; m < 4; m++)
#pragma unroll
        for (int n = 0; n < 4; n++)
            acc[m][n] = __builtin_amdgcn_mfma_f32_16x16x32_bf16(a[m], b[n], acc[m][n], 0, 0, 0);
    __builtin_amdgcn_s_setprio(0);
}

__device__ __forceinline__ void prologueF(const unsigned short* __restrict__ A,
                                          const unsigned short* __restrict__ Bm,
                                          int row0, int col0,
                                          unsigned short* lds, int w, int l) {
    stage_a(A,  row0, 0,  lds,                w, l);
    stage_b(Bm, col0, 0,  lds + 8192,         w, l);
    stage_a(A,  row0, 32, lds + BUF_,         w, l);
    stage_b(Bm, col0, 32, lds + BUF_ + 8192,  w, l);
}

template <bool DO_PROLOGUE>
__device__ __forceinline__ void kloopF(const unsigned short* __restrict__ A,
                                       const unsigned short* __restrict__ Bm,
                                       int row0, int col0,
                                       unsigned short* lds,   // 3 * BUF_
                                       int w, int l, f32x4 acc[4][4]) {
    const int lr = l & 15, lq = l >> 4;
    const int wrow = (w >> 1) * 64, wcol = (w & 1) * 64;

    if (DO_PROLOGUE) prologueF(A, Bm, row0, col0, lds, w, l);

#pragma unroll 3
    for (int t = 0; t < NKS_ - 2; ++t) {
        asm volatile("s_waitcnt vmcnt(3)" ::: "memory");
        __builtin_amdgcn_s_barrier();
        __builtin_amdgcn_sched_barrier(0);
        unsigned short* bn = lds + ((t + 2) % 3) * BUF_;
        stage_a(A,  row0, (t + 2) * 32, bn,        w, l);
        stage_b(Bm, col0, (t + 2) * 32, bn + 8192, w, l);
        unsigned short* bc = lds + (t % 3) * BUF_;
        tile_mfma44(bc, bc + 8192, wrow, wcol, lr, lq, acc);
    }
    asm volatile("s_waitcnt vmcnt(3)" ::: "memory");
    __builtin_amdgcn_s_barrier();
    __builtin_amdgcn_sched_barrier(0);
    {
        unsigned short* bc = lds + ((NKS_ - 2) % 3) * BUF_;
        tile_mfma44(bc, bc + 8192, wrow, wcol, lr, lq, acc);
    }
    asm volatile("s_waitcnt vmcnt(0)" ::: "memory");
    __builtin_amdgcn_s_barrier();
    __builtin_amdgcn_sched_barrier(0);
    {
        unsigned short* bc = lds + ((NKS_ - 1) % 3) * BUF_;
        tile_mfma44(bc, bc + 8192, wrow, wcol, lr, lq, acc);
    }
}

// ---------------------------------------------------------------------------
// Fused: gate = sigmoid(Xb@G^T+Gb) (packed bf16 in regs), then
//        out = x_bf + gelu(Sb@C^T) * gate.
// Block 256x128, 512 thr, grid 768 (6 col x 128 row), 2 blocks/CU. [proven]
// ---------------------------------------------------------------------------
__global__ __launch_bounds__(512, 2)
void gemm_fused_out(const unsigned short* __restrict__ Xb,
                    const unsigned short* __restrict__ Gwb,
                    const unsigned short* __restrict__ Sb,
                    const unsigned short* __restrict__ Cwb,
                    const float* __restrict__ Gbias,
                    float* __restrict__ out) {
    __shared__ unsigned short lds[3 * BUF_];
    const int t = threadIdx.x, l = t & 63, w = t >> 6;
    int rowt, colt;
    tile_decode(768, 6, rowt, colt);
    const int row0 = rowt * 256, col0 = colt * 128;
    const int lr = l & 15, lq = l >> 4;
    const int wrow = (w >> 1) * 64, wcol = (w & 1) * 64;

    // hoist Gbias so the gate pack is pure VALU (vmcnt stream stays clean)
    float gb[4];
#pragma unroll
    for (int n = 0; n < 4; n++) gb[n] = Gbias[col0 + wcol + n * 16 + lr];

    f32x4 acc[4][4] = {};
    kloopF<true>(Xb, Gwb, row0, col0, lds, w, l, acc);

    // issue kloop-C prologue now: HBM latency hides under the gate pack.
    // Safe: all buffer readers passed the final kloop-G barriers.
    prologueF(Sb, Cwb, row0, col0, lds, w, l);

    unsigned int gp[4][4][2];
#pragma unroll
    for (int m = 0; m < 4; m++)
#pragma unroll
        for (int n = 0; n < 4; n++) {
            gp[m][n][0] = (unsigned)f2bf(sigmoidf_(acc[m][n][0] + gb[n]))
                        | ((unsigned)f2bf(sigmoidf_(acc[m][n][1] + gb[n])) << 16);
            gp[m][n][1] = (unsigned)f2bf(sigmoidf_(acc[m][n][2] + gb[n]))
                        | ((unsigned)f2bf(sigmoidf_(acc[m][n][3] + gb[n])) << 16);
            acc[m][n] = (f32x4){0.f, 0.f, 0.f, 0.f};
        }

    kloopF<false>(Sb, Cwb, row0, col0, lds, w, l, acc);

#pragma unroll
    for (int m = 0; m < 4; m++)
#pragma unroll
        for (int n = 0; n < 4; n++) {
            int col = col0 + wcol + n * 16 + lr;
#pragma unroll
            for (int r = 0; r < 4; r++) {
                int row = row0 + wrow + m * 16 + lq * 4 + r;
                size_t o = (size_t)row * D_ + col;
                float g = bf2f((unsigned short)(gp[m][n][r >> 1] >> ((r & 1) * 16)));
                out[o] = bf2f(Xb[o]) + gelu_exact(acc[m][n][r]) * g;
            }
        }
}

// ===========================================================================
// E1 variant: 256 threads, block 128x128, wave tile 128x32 (acc[8][2]).
// Loads/thread/K-step = 4 (A 2 + B 2); vmcnt(4). 3 blocks/CU, grid 512.
// ===========================================================================
__device__ __forceinline__ void stage_e1(const unsigned short* __restrict__ A,
                                         const unsigned short* __restrict__ Bm,
                                         int row0, int col0, int k0,
                                         unsigned short* buf, int w, int l) {
#pragma unroll
    for (int j = 0; j < 2; ++j) {               // A: 128x32 = 512 chunks
        int i = ((w * 2 + j) << 6) + l;
        int row = i >> 2, q = i & 3;
        int qs = q ^ ((row >> 1) & 3);
        gload16(A + (size_t)(row0 + row) * D_ + k0 + qs * 8, buf + ((w * 2 + j) << 9));
    }
    unsigned short* bl = buf + 4096;
#pragma unroll
    for (int j = 0; j < 2; ++j) {               // B: 128x32 = 512 chunks
        int i = ((w * 2 + j) << 6) + l;
        int row = i >> 2, q = i & 3;
        int qs = q ^ ((row >> 1) & 3);
        gload16(Bm + (size_t)(col0 + row) * D_ + k0 + qs * 8, bl + ((w * 2 + j) << 9));
    }
}

__device__ __forceinline__ void tile_mfma82(const unsigned short* buf,
                                            int wcol, int lr, int lq,
                                            f32x4 acc[8][2]) {
    const unsigned short* la = buf;
    const unsigned short* lb = buf + 4096;
    bf16x8 b[2];
#pragma unroll
    for (int n = 0; n < 2; n++) b[n] = frag_read(lb, wcol + n * 16 + lr, lq);
    __builtin_amdgcn_s_setprio(1);
#pragma unroll
    for (int m = 0; m < 8; m++) {
        bf16x8 a = frag_read(la, m * 16 + lr, lq);
#pragma unroll
        for (int n = 0; n < 2; n++)
            acc[m][n] = __builtin_amdgcn_mfma_f32_16x16x32_bf16(a, b[n], acc[m][n], 0, 0, 0);
    }
    __builtin_amdgcn_s_setprio(0);
}

__device__ __forceinline__ void kloopE1(const unsigned short* __restrict__ A,
                                        const unsigned short* __restrict__ Bm,
                                        int row0, int col0,
                                        unsigned short* lds,   // 3 * BUFE1
                                        int w, int l, f32x4 acc[8][2]) {
    const int lr = l & 15, lq = l >> 4;
    const int wcol = w * 32;

    stage_e1(A, Bm, row0, col0, 0,  lds,         w, l);
    stage_e1(A, Bm, row0, col0, 32, lds + BUFE1, w, l);

#pragma unroll 3
    for (int t = 0; t < NKS_ - 2; ++t) {
        asm volatile("s_waitcnt vmcnt(4)" ::: "memory");
        __builtin_amdgcn_s_barrier();
        __builtin_amdgcn_sched_barrier(0);
        stage_e1(A, Bm, row0, col0, (t + 2) * 32, lds + ((t + 2) % 3) * BUFE1, w, l);
        tile_mfma82(lds + (t % 3) * BUFE1, wcol, lr, lq, acc);
    }
    asm volatile("s_waitcnt vmcnt(4)" ::: "memory");
    __builtin_amdgcn_s_barrier();
    __builtin_amdgcn_sched_barrier(0);
    tile_mfma82(lds + ((NKS_ - 2) % 3) * BUFE1, wcol, lr, lq, acc);
    asm volatile("s_waitcnt vmcnt(0)" ::: "memory");
    __builtin_amdgcn_s_barrier();
    __builtin_amdgcn_sched_barrier(0);
    tile_mfma82(lds + ((NKS_ - 1) % 3) * BUFE1, wcol, lr, lq, acc);
}

// ---------------------------------------------------------------------------
// E1 GEMM + alpha partials (H never materialized). Block 128x128, 256 thr,
// grid 512 (2 col x 256 row) -> full chip at 3 blocks/CU.
// ---------------------------------------------------------------------------
__global__ __launch_bounds__(256, 3)
void gemm_e1_alpha(const unsigned short* __restrict__ Xb,
                   const unsigned short* __restrict__ Wb,
                   const float* __restrict__ bias,
                   const float* __restrict__ E2w,
                   float* __restrict__ alpha_acc) {
    __shared__ unsigned short lds[3 * BUFE1];
    const int t = threadIdx.x, l = t & 63, w = t >> 6;
    int rowt, colt;
    tile_decode(512, 2, rowt, colt);
    const int row0 = rowt * 128, col0 = colt * 128;
    const int lr = l & 15, lq = l >> 4;
    const int wcol = w * 32;
    f32x4 acc[8][2] = {};
    kloopE1(Xb, Wb, row0, col0, lds, w, l, acc);

    float bia[2], e2v[3][2];
#pragma unroll
    for (int n = 0; n < 2; n++) {
        int col = col0 + wcol + n * 16 + lr;
        bia[n] = bias[col];
#pragma unroll
        for (int c = 0; c < 3; c++) e2v[c][n] = E2w[c * DB_ + col];
    }
#pragma unroll
    for (int m = 0; m < 8; m++)
#pragma unroll
        for (int r = 0; r < 4; r++) {
            float p0 = 0.f, p1 = 0.f, p2 = 0.f;
#pragma unroll
            for (int n = 0; n < 2; n++) {
                float h = gelu_exact(acc[m][n][r] + bia[n]);
                p0 = fmaf(h, e2v[0][n], p0);
                p1 = fmaf(h, e2v[1][n], p1);
                p2 = fmaf(h, e2v[2][n], p2);
            }
#pragma unroll
            for (int s = 1; s < 16; s <<= 1) {
                p0 += __shfl_xor(p0, s);
                p1 += __shfl_xor(p1, s);
                p2 += __shfl_xor(p2, s);
            }
            if (lr == 0) {
                int row = row0 + m * 16 + lq * 4 + r;
                atomicAdd(&alpha_acc[(size_t)row * 3 + 0], p0);
                atomicAdd(&alpha_acc[(size_t)row * 3 + 1], p1);
                atomicAdd(&alpha_acc[(size_t)row * 3 + 2], p2);
            }
        }
}

// ---------------------------------------------------------------------------
// Fused cvt + Z, split-K: block = 2 waves; wave w handles K half [w*384,+384).
// Each wave: 16 tokens, 12-MFMA chain; Z combined via LDS. grid 2048.
// ---------------------------------------------------------------------------
__global__ __launch_bounds__(128)
void cvtz_kernel(const float* __restrict__ X, const float* __restrict__ Vw,
                 unsigned short* __restrict__ Xb, float* __restrict__ Z) {
    __shared__ float zs[16 * 16];
    const int t = threadIdx.x, l = t & 63, w = t >> 6;   // 2 waves
    const int lr = l & 15, lq = l >> 4;
    const int tok0 = blockIdx.x * 16;
    const int kbase = w * (D_ / 2);
    const float* xrow = X  + (size_t)(tok0 + lr) * D_ + kbase;
    const float* vrow = Vw + (size_t)lr * D_ + kbase;
    f32x4 acc = {};
#pragma unroll 4
    for (int k0 = 0; k0 < D_ / 2; k0 += 32) {
        int k = k0 + lq * 8;
        float4 xa = *(const float4*)&xrow[k];
        float4 xb = *(const float4*)&xrow[k + 4];
        float4 va = *(const float4*)&vrow[k];
        float4 vb = *(const float4*)&vrow[k + 4];
        bf16x8 xf = pack8(xa, xb);
        bf16x8 vf = pack8(va, vb);
        *(bf16x8*)&Xb[(size_t)(tok0 + lr) * D_ + kbase + k] = xf;
        acc = __builtin_amdgcn_mfma_f32_16x16x32_bf16(xf, vf, acc, 0, 0, 0);
    }
    if (w == 1) {
#pragma unroll
        for (int rr = 0; rr < 4; rr++) zs[(lq * 4 + rr) * 16 + lr] = acc[rr];
    }
    __syncthreads();
    if (w == 0) {
#pragma unroll
        for (int rr = 0; rr < 4; rr++)
            Z[(size_t)(tok0 + lq * 4 + rr) * R_ + lr] = acc[rr] + zs[(lq * 4 + rr) * 16 + lr];
    }
}

// ---------------------------------------------------------------------------
// Merged setup: cvt E1/C/G to bf16, zero alpha accumulator, tanh(a_delta).
// ---------------------------------------------------------------------------
#define SEG_E1  (DB_ * D_ / 4)             // 49152
#define SEG_W   (D_ * D_ / 4)              // 147456
#define SEG_Z   (N_ * 3 / 4)               // 24576
#define SEG_TOT (SEG_E1 + 2 * SEG_W + SEG_Z + 192)

__global__ void setup_all(const float* __restrict__ E1_w, const float* __restrict__ C_w,
                          const float* __restrict__ G_w, const float* __restrict__ a_delta,
                          unsigned short* __restrict__ E1b, unsigned short* __restrict__ Cwb,
                          unsigned short* __restrict__ Gwb, float* __restrict__ al_acc,
                          float* __restrict__ tanhd) {
    int i = blockIdx.x * 256 + threadIdx.x;
    if (i < SEG_E1) {
        float4 v = ((const float4*)E1_w)[i];
        ((ushort4*)E1b)[i] = make_ushort4(f2bf(v.x), f2bf(v.y), f2bf(v.z), f2bf(v.w));
    } else if (i < SEG_E1 + SEG_W) {
        int j = i - SEG_E1;
        float4 v = ((const float4*)C_w)[j];
        ((ushort4*)Cwb)[j] = make_ushort4(f2bf(v.x), f2bf(v.y), f2bf(v.z), f2bf(v.w));
    } else if (i < SEG_E1 + 2 * SEG_W) {
        int j = i - SEG_E1 - SEG_W;
        float4 v = ((const float4*)G_w)[j];
        ((ushort4*)Gwb)[j] = make_ushort4(f2bf(v.x), f2bf(v.y), f2bf(v.z), f2bf(v.w));
    } else if (i < SEG_E1 + 2 * SEG_W + SEG_Z) {
        int j = i - SEG_E1 - 2 * SEG_W;
        ((float4*)al_acc)[j] = make_float4(0.f, 0.f, 0.f, 0.f);
    } else if (i < SEG_TOT) {
        int j = (i - SEG_E1 - 2 * SEG_W - SEG_Z) * 4;
        tanhd[j + 0] = tanhf(a_delta[j + 0]);
        tanhd[j + 1] = tanhf(a_delta[j + 1]);
        tanhd[j + 2] = tanhf(a_delta[j + 2]);
        tanhd[j + 3] = tanhf(a_delta[j + 3]);
    }
}

// ---------------------------------------------------------------------------
// Scan with on-the-fly lam/bu recompute; alpha finalized inline.
// ---------------------------------------------------------------------------
__device__ __forceinline__ void load_chunk_lds(const float* __restrict__ Z,
                                               const float* __restrict__ al_acc,
                                               const float* __restrict__ E2b,
                                               int tok0, int t,
                                               float* Zs, float* als) {
#pragma unroll
    for (int i = t; i < L_ * R_ / 4; i += 192)
        *(float4*)&Zs[i * 4] = *(const float4*)&Z[(size_t)tok0 * R_ + i * 4];
    als[t] = sigmoidf_(al_acc[(size_t)tok0 * 3 + t] + E2b[t % 3]);   // 192 = 64*3
}

__device__ __forceinline__ float dot16(const float* zrow, const float4* u) {
    float4 z0 = *(const float4*)&zrow[0],  z1 = *(const float4*)&zrow[4];
    float4 z2 = *(const float4*)&zrow[8],  z3 = *(const float4*)&zrow[12];
    return z0.x*u[0].x + z0.y*u[0].y + z0.z*u[0].z + z0.w*u[0].w
         + z1.x*u[1].x + z1.y*u[1].y + z1.z*u[1].z + z1.w*u[1].w
         + z2.x*u[2].x + z2.y*u[2].y + z2.z*u[2].z + z2.w*u[2].w
         + z3.x*u[3].x + z3.y*u[3].y + z3.z*u[3].z + z3.w*u[3].w;
}

__global__ __launch_bounds__(192)
void scan_pass1(const float* __restrict__ Z, const float* __restrict__ al_acc,
                const float* __restrict__ E2b,
                const float* __restrict__ Uw, const float* __restrict__ a_base,
                const float* __restrict__ tanhd,
                float* __restrict__ Aagg, float* __restrict__ Send) {
    __shared__ float Zs[L_ * R_];
    __shared__ float als[L_ * 3];
    const int t = threadIdx.x;
    const int c = blockIdx.x & (NC_ - 1);
    const int b = blockIdx.x >> 6;
    const int tok0 = b * T_ + c * L_;
    const int d0 = t * 4;
    const int buck = d0 >> 8;
    load_chunk_lds(Z, al_acc, E2b, tok0, t, Zs, als);

    float4 u[4][4];
#pragma unroll
    for (int j = 0; j < 4; j++)
#pragma unroll
        for (int q = 0; q < 4; q++)
            u[j][q] = *(const float4*)&Uw[(size_t)(d0 + j) * R_ + q * 4];
    float4 ab = *(const float4*)&a_base[d0];
    float4 td = *(const float4*)&tanhd[d0];
    float abv[4] = {ab.x, ab.y, ab.z, ab.w};
    float tdv[4] = {td.x, td.y, td.z, td.w};
    __syncthreads();

    float a[4] = {1.f, 1.f, 1.f, 1.f}, s[4] = {};
    for (int i = 0; i < L_; i++) {
        float av = als[i * 3 + buck];
#pragma unroll
        for (int j = 0; j < 4; j++) {
            float lam = sigmoidf_(fmaf(av, tdv[j], abv[j]));
            float bu  = dot16(&Zs[i * R_], u[j]);
            a[j] *= lam;
            s[j] = fmaf(lam, s[j], bu);
        }
    }
    size_t o = ((size_t)(b * NC_ + c)) * D_ + d0;
    *(float4*)&Aagg[o] = make_float4(a[0], a[1], a[2], a[3]);
    *(float4*)&Send[o] = make_float4(s[0], s[1], s[2], s[3]);
}

__global__ void scan_pass2(const float* __restrict__ Aagg, const float* __restrict__ Send,
                           float* __restrict__ Cin) {
    const int d = threadIdx.x;              // 768 threads
    const int b = blockIdx.x;               // 8 blocks
    float s = 0.f;
    for (int c = 0; c < NC_; c++) {
        size_t o = ((size_t)(b * NC_ + c)) * D_ + d;
        Cin[o] = s;
        s = fmaf(Aagg[o], s, Send[o]);
    }
}

__global__ __launch_bounds__(192)
void scan_pass3(const float* __restrict__ Z, const float* __restrict__ al_acc,
                const float* __restrict__ E2b,
                const float* __restrict__ Uw, const float* __restrict__ a_base,
                const float* __restrict__ tanhd, const float* __restrict__ Cin,
                unsigned short* __restrict__ Sout) {
    __shared__ float Zs[L_ * R_];
    __shared__ float als[L_ * 3];
    const int t = threadIdx.x;
    const int c = blockIdx.x & (NC_ - 1);
    const int b = blockIdx.x >> 6;
    const int tok0 = b * T_ + c * L_;
    const int d0 = t * 4;
    const int buck = d0 >> 8;
    load_chunk_lds(Z, al_acc, E2b, tok0, t, Zs, als);

    float4 u[4][4];
#pragma unroll
    for (int j = 0; j < 4; j++)
#pragma unroll
        for (int q = 0; q < 4; q++)
            u[j][q] = *(const float4*)&Uw[(size_t)(d0 + j) * R_ + q * 4];
    float4 ab = *(const float4*)&a_base[d0];
    float4 td = *(const float4*)&tanhd[d0];
    float abv[4] = {ab.x, ab.y, ab.z, ab.w};
    float tdv[4] = {td.x, td.y, td.z, td.w};
    __syncthreads();

    size_t ci = ((size_t)(b * NC_ + c)) * D_ + d0;
    float4 c4 = *(const float4*)&Cin[ci];
    float s[4] = {c4.x, c4.y, c4.z, c4.w};
    for (int i = 0; i < L_; i++) {
        float av = als[i * 3 + buck];
#pragma unroll
        for (int j = 0; j < 4; j++) {
            float lam = sigmoidf_(fmaf(av, tdv[j], abv[j]));
            float bu  = dot16(&Zs[i * R_], u[j]);
            s[j] = fmaf(lam, s[j], bu);
        }
        *(ushort4*)&Sout[(size_t)(tok0 + i) * D_ + d0] =
            make_ushort4(f2bf(s[0]), f2bf(s[1]), f2bf(s[2]), f2bf(s[3]));
    }
}

// ---------------------------------------------------------------------------
extern "C" void kernel_launch(void* const* d_in, const int* in_sizes, int n_in,
                              void* d_out, int out_size, void* d_ws, size_t ws_size,
                              hipStream_t stream) {
    const float* x       = (const float*)d_in[0];
    const float* V_w     = (const float*)d_in[1];
    const float* U_w     = (const float*)d_in[2];
    const float* E1_w    = (const float*)d_in[3];
    const float* E1_b    = (const float*)d_in[4];
    const float* E2_w    = (const float*)d_in[5];
    const float* E2_b    = (const float*)d_in[6];
    const float* a_base  = (const float*)d_in[7];
    const float* a_delta = (const float*)d_in[8];
    const float* C_w     = (const float*)d_in[9];
    const float* G_w     = (const float*)d_in[10];
    const float* G_b     = (const float*)d_in[11];
    float* out = (float*)d_out;

    // workspace layout
    char* p = (char*)d_ws;
    float* Aagg   = (float*)p;          p += (size_t)B_ * NC_ * D_ * 4;
    float* Send   = (float*)p;          p += (size_t)B_ * NC_ * D_ * 4;
    float* Cin    = (float*)p;          p += (size_t)B_ * NC_ * D_ * 4;
    float* tanhd  = (float*)p;          p += (size_t)D_ * 4;
    float* Z      = (float*)p;          p += (size_t)N_ * R_ * 4;
    float* al_acc = (float*)p;          p += (size_t)N_ * 3 * 4;
    unsigned short* x_bf  = (unsigned short*)p; p += (size_t)N_ * D_ * 2;
    unsigned short* S_bf  = (unsigned short*)p; p += (size_t)N_ * D_ * 2;
    unsigned short* E1_bf = (unsigned short*)p; p += (size_t)DB_ * D_ * 2;
    unsigned short* Cw_bf = (unsigned short*)p; p += (size_t)D_ * D_ * 2;
    unsigned short* Gw_bf = (unsigned short*)p; p += (size_t)D_ * D_ * 2;

    // merged setup (weights cvt + zero + tanh) — one launch
    setup_all<<<(SEG_TOT + 255) / 256, 256, 0, stream>>>(
        E1_w, C_w, G_w, a_delta, E1_bf, Cw_bf, Gw_bf, al_acc, tanhd);

    // x -> bf16 and Z = x@V^T in one pass (split-K, 2 waves/block)
    cvtz_kernel<<<N_ / 16, 128, 0, stream>>>(x, V_w, x_bf, Z);

    // E1 GEMM with fused alpha partials (H never materialized)
    gemm_e1_alpha<<<512, 256, 0, stream>>>(x_bf, E1_bf, E1_b, E2_w, al_acc);

    scan_pass1<<<B_ * NC_, 192, 0, stream>>>(Z, al_acc, E2_b, U_w, a_base, tanhd, Aagg, Send);
    scan_pass2<<<B_,       D_,  0, stream>>>(Aagg, Send, Cin);
    scan_pass3<<<B_ * NC_, 192, 0, stream>>>(Z, al_acc, E2_b, U_w, a_base, tanhd, Cin, S_bf);

    gemm_fused_out<<<768, 512, 0, stream>>>(x_bf, Gw_bf, S_bf, Cw_bf, G_b, out);
}

// Round 11
// 290.624 us; speedup vs baseline: 1.3905x; 1.1359x over previous
//
#include <hip/hip_runtime.h>
#include <hip/hip_bf16.h>
#include <math.h>

// Problem constants
#define B_   8
#define T_   4096
#define D_   768
#define R_   16
#define DB_  256
#define N_   (B_ * T_)      // 32768 tokens
#define NC_  64             // scan chunks per sequence
#define L_   (T_ / NC_)     // 64 steps per chunk
#define NKS_ (D_ / 32)      // 24 K-steps of 32
#define BUF_ 12288          // pipeline buffer: A 256x32 + B 128x32 (elems)

typedef __attribute__((ext_vector_type(8))) short bf16x8;
typedef __attribute__((ext_vector_type(4))) float f32x4;

__device__ __forceinline__ float gelu_exact(float x) {
    return 0.5f * x * (1.0f + erff(x * 0.70710678118654752f));
}
__device__ __forceinline__ float sigmoidf_(float x) {
    return 1.0f / (1.0f + expf(-x));
}
__device__ __forceinline__ float bf2f(unsigned short u) {
    return __uint_as_float(((unsigned)u) << 16);
}
__device__ __forceinline__ unsigned short f2bf(float f) {
    __hip_bfloat16 h = __float2bfloat16(f);   // RNE
    return *(unsigned short*)&h;
}
__device__ __forceinline__ bf16x8 pack8(float4 a, float4 b) {
    bf16x8 r;
    r[0] = (short)f2bf(a.x); r[1] = (short)f2bf(a.y);
    r[2] = (short)f2bf(a.z); r[3] = (short)f2bf(a.w);
    r[4] = (short)f2bf(b.x); r[5] = (short)f2bf(b.y);
    r[6] = (short)f2bf(b.z); r[7] = (short)f2bf(b.w);
    return r;
}

// async global->LDS, 16B per lane. LDS dest = wave-uniform base + lane*16.
__device__ __forceinline__ void gload16(const unsigned short* g, unsigned short* l) {
    __builtin_amdgcn_global_load_lds(
        (const __attribute__((address_space(1))) unsigned int*)(const void*)g,
        (__attribute__((address_space(3))) unsigned int*)(void*)l,
        16, 0, 0);
}

// swizzled LDS fragment read: 8 bf16 for mfma_16x16x32 (bank-conflict-free;
// source quad was pre-swizzled with the same q ^= (row>>1)&3 — rule 21)
__device__ __forceinline__ bf16x8 frag_read(const unsigned short* lds, int row, int lq) {
    int q = lq ^ ((row >> 1) & 3);
    return *(const bf16x8*)(lds + row * 32 + q * 8);
}

// chunked XCD swizzle (nwg % 8 == 0), then col-fastest decode
__device__ __forceinline__ void tile_decode(int nwg, int ncol, int& rowt, int& colt) {
    int bid = blockIdx.x;
    int cpx = nwg >> 3;
    int swz = (bid & 7) * cpx + (bid >> 3);
    colt = swz % ncol;
    rowt = swz / ncol;
}

// ===========================================================================
// Proven GEMM variant (124 us fused): 512 threads, block 256x128,
// wave tile 64x64 (wave grid 4x2). Loads/thread/K-step = 3; vmcnt(3);
// 3-buffer counted-vmcnt pipeline, never drained to 0 in the main loop.
// ===========================================================================
__device__ __forceinline__ void stage_a(const unsigned short* src, int row0, int k0,
                                        unsigned short* lds, int w, int l) {
#pragma unroll
    for (int j = 0; j < 2; ++j) {
        int i = ((w * 2 + j) << 6) + l;     // 0..1023 (256 rows x 4 quads)
        int row = i >> 2, q = i & 3;
        int qs = q ^ ((row >> 1) & 3);
        gload16(src + (size_t)(row0 + row) * D_ + k0 + qs * 8, lds + ((w * 2 + j) << 9));
    }
}
__device__ __forceinline__ void stage_b(const unsigned short* src, int col0, int k0,
                                        unsigned short* lds, int w, int l) {
    int i = (w << 6) + l;                   // 0..511 (128 rows x 4 quads)
    int row = i >> 2, q = i & 3;
    int qs = q ^ ((row >> 1) & 3);
    gload16(src + (size_t)(col0 + row) * D_ + k0 + qs * 8, lds + (w << 9));
}

__device__ __forceinline__ void tile_mfma44(const unsigned short* la, const unsigned short* lb,
                                            int wrow, int wcol, int lr, int lq,
                                            f32x4 acc[4][4]) {
    bf16x8 a[4], b[4];
#pragma unroll
    for (int m = 0; m < 4; m++) a[m] = frag_read(la, wrow + m * 16 + lr, lq);
#pragma unroll
    for (int n = 0; n < 4; n++) b[n] = frag_read(lb, wcol + n * 16 + lr, lq);
    __builtin_amdgcn_s_setprio(1);
#pragma unroll
    for (int m = 0; m < 4; m++)
#pragma unroll
        for (int n = 0; n < 4; n++)
            acc[m][n] = __builtin_amdgcn_mfma_f32_16x16x32_bf16(a[m], b[n], acc[m][n], 0, 0, 0);
    __builtin_amdgcn_s_setprio(0);
}

__device__ __forceinline__ void prologueF(const unsigned short* __restrict__ A,
                                          const unsigned short* __restrict__ Bm,
                                          int row0, int col0,
                                          unsigned short* lds, int w, int l) {
    stage_a(A,  row0, 0,  lds,                w, l);
    stage_b(Bm, col0, 0,  lds + 8192,         w, l);
    stage_a(A,  row0, 32, lds + BUF_,         w, l);
    stage_b(Bm, col0, 32, lds + BUF_ + 8192,  w, l);
}

template <bool DO_PROLOGUE>
__device__ __forceinline__ void kloopF(const unsigned short* __restrict__ A,
                                       const unsigned short* __restrict__ Bm,
                                       int row0, int col0,
                                       unsigned short* lds,   // 3 * BUF_
                                       int w, int l, f32x4 acc[4][4]) {
    const int lr = l & 15, lq = l >> 4;
    const int wrow = (w >> 1) * 64, wcol = (w & 1) * 64;

    if (DO_PROLOGUE) prologueF(A, Bm, row0, col0, lds, w, l);

#pragma unroll 3
    for (int t = 0; t < NKS_ - 2; ++t) {
        asm volatile("s_waitcnt vmcnt(3)" ::: "memory");
        __builtin_amdgcn_s_barrier();
        __builtin_amdgcn_sched_barrier(0);
        unsigned short* bn = lds + ((t + 2) % 3) * BUF_;
        stage_a(A,  row0, (t + 2) * 32, bn,        w, l);
        stage_b(Bm, col0, (t + 2) * 32, bn + 8192, w, l);
        unsigned short* bc = lds + (t % 3) * BUF_;
        tile_mfma44(bc, bc + 8192, wrow, wcol, lr, lq, acc);
    }
    asm volatile("s_waitcnt vmcnt(3)" ::: "memory");
    __builtin_amdgcn_s_barrier();
    __builtin_amdgcn_sched_barrier(0);
    {
        unsigned short* bc = lds + ((NKS_ - 2) % 3) * BUF_;
        tile_mfma44(bc, bc + 8192, wrow, wcol, lr, lq, acc);
    }
    asm volatile("s_waitcnt vmcnt(0)" ::: "memory");
    __builtin_amdgcn_s_barrier();
    __builtin_amdgcn_sched_barrier(0);
    {
        unsigned short* bc = lds + ((NKS_ - 1) % 3) * BUF_;
        tile_mfma44(bc, bc + 8192, wrow, wcol, lr, lq, acc);
    }
}

// ---------------------------------------------------------------------------
// Fused: gate = sigmoid(Xb@G^T+Gb) (packed bf16 in regs), then
//        out = x_bf + gelu(Sb@C^T) * gate.
// Block 256x128, 512 thr, grid 768 (6 col x 128 row), 2 blocks/CU. [proven]
// ---------------------------------------------------------------------------
__global__ __launch_bounds__(512, 2)
void gemm_fused_out(const unsigned short* __restrict__ Xb,
                    const unsigned short* __restrict__ Gwb,
                    const unsigned short* __restrict__ Sb,
                    const unsigned short* __restrict__ Cwb,
                    const float* __restrict__ Gbias,
                    float* __restrict__ out) {
    __shared__ unsigned short lds[3 * BUF_];
    const int t = threadIdx.x, l = t & 63, w = t >> 6;
    int rowt, colt;
    tile_decode(768, 6, rowt, colt);
    const int row0 = rowt * 256, col0 = colt * 128;
    const int lr = l & 15, lq = l >> 4;
    const int wrow = (w >> 1) * 64, wcol = (w & 1) * 64;

    // hoist Gbias so the gate pack is pure VALU (vmcnt stream stays clean)
    float gb[4];
#pragma unroll
    for (int n = 0; n < 4; n++) gb[n] = Gbias[col0 + wcol + n * 16 + lr];

    f32x4 acc[4][4] = {};
    kloopF<true>(Xb, Gwb, row0, col0, lds, w, l, acc);

    // issue kloop-C prologue now: HBM latency hides under the gate pack.
    // Safe: all buffer readers passed the final kloop-G barriers.
    prologueF(Sb, Cwb, row0, col0, lds, w, l);

    unsigned int gp[4][4][2];
#pragma unroll
    for (int m = 0; m < 4; m++)
#pragma unroll
        for (int n = 0; n < 4; n++) {
            gp[m][n][0] = (unsigned)f2bf(sigmoidf_(acc[m][n][0] + gb[n]))
                        | ((unsigned)f2bf(sigmoidf_(acc[m][n][1] + gb[n])) << 16);
            gp[m][n][1] = (unsigned)f2bf(sigmoidf_(acc[m][n][2] + gb[n]))
                        | ((unsigned)f2bf(sigmoidf_(acc[m][n][3] + gb[n])) << 16);
            acc[m][n] = (f32x4){0.f, 0.f, 0.f, 0.f};
        }

    kloopF<false>(Sb, Cwb, row0, col0, lds, w, l, acc);

#pragma unroll
    for (int m = 0; m < 4; m++)
#pragma unroll
        for (int n = 0; n < 4; n++) {
            int col = col0 + wcol + n * 16 + lr;
#pragma unroll
            for (int r = 0; r < 4; r++) {
                int row = row0 + wrow + m * 16 + lq * 4 + r;
                size_t o = (size_t)row * D_ + col;
                float g = bf2f((unsigned short)(gp[m][n][r >> 1] >> ((r & 1) * 16)));
                out[o] = bf2f(Xb[o]) + gelu_exact(acc[m][n][r]) * g;
            }
        }
}

// ---------------------------------------------------------------------------
// E1 GEMM + alpha partials (H never materialized). Same proven kloopF:
// block 256x128, 512 thr, grid 256 (2 col x 128 row).
// ---------------------------------------------------------------------------
__global__ __launch_bounds__(512, 2)
void gemm_e1_alpha(const unsigned short* __restrict__ Xb,
                   const unsigned short* __restrict__ Wb,
                   const float* __restrict__ bias,
                   const float* __restrict__ E2w,
                   float* __restrict__ alpha_acc) {
    __shared__ unsigned short lds[3 * BUF_];
    const int t = threadIdx.x, l = t & 63, w = t >> 6;
    int rowt, colt;
    tile_decode(256, 2, rowt, colt);
    const int row0 = rowt * 256, col0 = colt * 128;
    const int lr = l & 15, lq = l >> 4;
    const int wrow = (w >> 1) * 64, wcol = (w & 1) * 64;
    f32x4 acc[4][4] = {};
    kloopF<true>(Xb, Wb, row0, col0, lds, w, l, acc);

    float bia[4], e2v[3][4];
#pragma unroll
    for (int n = 0; n < 4; n++) {
        int col = col0 + wcol + n * 16 + lr;
        bia[n] = bias[col];
#pragma unroll
        for (int c = 0; c < 3; c++) e2v[c][n] = E2w[c * DB_ + col];
    }
#pragma unroll
    for (int m = 0; m < 4; m++)
#pragma unroll
        for (int r = 0; r < 4; r++) {
            float p0 = 0.f, p1 = 0.f, p2 = 0.f;
#pragma unroll
            for (int n = 0; n < 4; n++) {
                float h = gelu_exact(acc[m][n][r] + bia[n]);
                p0 = fmaf(h, e2v[0][n], p0);
                p1 = fmaf(h, e2v[1][n], p1);
                p2 = fmaf(h, e2v[2][n], p2);
            }
#pragma unroll
            for (int s = 1; s < 16; s <<= 1) {
                p0 += __shfl_xor(p0, s);
                p1 += __shfl_xor(p1, s);
                p2 += __shfl_xor(p2, s);
            }
            if (lr == 0) {
                int row = row0 + wrow + m * 16 + lq * 4 + r;
                atomicAdd(&alpha_acc[(size_t)row * 3 + 0], p0);
                atomicAdd(&alpha_acc[(size_t)row * 3 + 1], p1);
                atomicAdd(&alpha_acc[(size_t)row * 3 + 2], p2);
            }
        }
}

// ---------------------------------------------------------------------------
// Fused cvt + Z: x_bf = bf16(x);  Z = x_bf @ V^T (V converted on the fly).
// One wave = 16 tokens; block = 4 waves = 64 tokens; grid 512. [R9-proven]
// ---------------------------------------------------------------------------
__global__ __launch_bounds__(256)
void cvtz_kernel(const float* __restrict__ X, const float* __restrict__ Vw,
                 unsigned short* __restrict__ Xb, float* __restrict__ Z) {
    const int t = threadIdx.x, l = t & 63, w = t >> 6;
    const int lr = l & 15, lq = l >> 4;
    const int tok0 = (blockIdx.x * 4 + w) * 16;
    const float* xrow = X  + (size_t)(tok0 + lr) * D_;
    const float* vrow = Vw + (size_t)lr * D_;
    f32x4 acc = {};
#pragma unroll 4
    for (int k0 = 0; k0 < D_; k0 += 32) {
        int k = k0 + lq * 8;
        float4 xa = *(const float4*)&xrow[k];
        float4 xb = *(const float4*)&xrow[k + 4];
        float4 va = *(const float4*)&vrow[k];
        float4 vb = *(const float4*)&vrow[k + 4];
        bf16x8 xf = pack8(xa, xb);
        bf16x8 vf = pack8(va, vb);
        *(bf16x8*)&Xb[(size_t)(tok0 + lr) * D_ + k] = xf;
        acc = __builtin_amdgcn_mfma_f32_16x16x32_bf16(xf, vf, acc, 0, 0, 0);
    }
#pragma unroll
    for (int rr = 0; rr < 4; rr++)
        Z[(size_t)(tok0 + lq * 4 + rr) * R_ + lr] = acc[rr];
}

// ---------------------------------------------------------------------------
// Merged setup: cvt E1/C/G to bf16, zero alpha accumulator, tanh(a_delta).
// ---------------------------------------------------------------------------
#define SEG_E1  (DB_ * D_ / 4)             // 49152
#define SEG_W   (D_ * D_ / 4)              // 147456
#define SEG_Z   (N_ * 3 / 4)               // 24576
#define SEG_TOT (SEG_E1 + 2 * SEG_W + SEG_Z + 192)

__global__ void setup_all(const float* __restrict__ E1_w, const float* __restrict__ C_w,
                          const float* __restrict__ G_w, const float* __restrict__ a_delta,
                          unsigned short* __restrict__ E1b, unsigned short* __restrict__ Cwb,
                          unsigned short* __restrict__ Gwb, float* __restrict__ al_acc,
                          float* __restrict__ tanhd) {
    int i = blockIdx.x * 256 + threadIdx.x;
    if (i < SEG_E1) {
        float4 v = ((const float4*)E1_w)[i];
        ((ushort4*)E1b)[i] = make_ushort4(f2bf(v.x), f2bf(v.y), f2bf(v.z), f2bf(v.w));
    } else if (i < SEG_E1 + SEG_W) {
        int j = i - SEG_E1;
        float4 v = ((const float4*)C_w)[j];
        ((ushort4*)Cwb)[j] = make_ushort4(f2bf(v.x), f2bf(v.y), f2bf(v.z), f2bf(v.w));
    } else if (i < SEG_E1 + 2 * SEG_W) {
        int j = i - SEG_E1 - SEG_W;
        float4 v = ((const float4*)G_w)[j];
        ((ushort4*)Gwb)[j] = make_ushort4(f2bf(v.x), f2bf(v.y), f2bf(v.z), f2bf(v.w));
    } else if (i < SEG_E1 + 2 * SEG_W + SEG_Z) {
        int j = i - SEG_E1 - 2 * SEG_W;
        ((float4*)al_acc)[j] = make_float4(0.f, 0.f, 0.f, 0.f);
    } else if (i < SEG_TOT) {
        int j = (i - SEG_E1 - 2 * SEG_W - SEG_Z) * 4;
        tanhd[j + 0] = tanhf(a_delta[j + 0]);
        tanhd[j + 1] = tanhf(a_delta[j + 1]);
        tanhd[j + 2] = tanhf(a_delta[j + 2]);
        tanhd[j + 3] = tanhf(a_delta[j + 3]);
    }
}

// ---------------------------------------------------------------------------
// Scan with on-the-fly lam/bu recompute; alpha finalized inline.
// ---------------------------------------------------------------------------
__device__ __forceinline__ void load_chunk_lds(const float* __restrict__ Z,
                                               const float* __restrict__ al_acc,
                                               const float* __restrict__ E2b,
                                               int tok0, int t,
                                               float* Zs, float* als) {
#pragma unroll
    for (int i = t; i < L_ * R_ / 4; i += 192)
        *(float4*)&Zs[i * 4] = *(const float4*)&Z[(size_t)tok0 * R_ + i * 4];
    als[t] = sigmoidf_(al_acc[(size_t)tok0 * 3 + t] + E2b[t % 3]);   // 192 = 64*3
}

__device__ __forceinline__ float dot16(const float* zrow, const float4* u) {
    float4 z0 = *(const float4*)&zrow[0],  z1 = *(const float4*)&zrow[4];
    float4 z2 = *(const float4*)&zrow[8],  z3 = *(const float4*)&zrow[12];
    return z0.x*u[0].x + z0.y*u[0].y + z0.z*u[0].z + z0.w*u[0].w
         + z1.x*u[1].x + z1.y*u[1].y + z1.z*u[1].z + z1.w*u[1].w
         + z2.x*u[2].x + z2.y*u[2].y + z2.z*u[2].z + z2.w*u[2].w
         + z3.x*u[3].x + z3.y*u[3].y + z3.z*u[3].z + z3.w*u[3].w;
}

__global__ __launch_bounds__(192)
void scan_pass1(const float* __restrict__ Z, const float* __restrict__ al_acc,
                const float* __restrict__ E2b,
                const float* __restrict__ Uw, const float* __restrict__ a_base,
                const float* __restrict__ tanhd,
                float* __restrict__ Aagg, float* __restrict__ Send) {
    __shared__ float Zs[L_ * R_];
    __shared__ float als[L_ * 3];
    const int t = threadIdx.x;
    const int c = blockIdx.x & (NC_ - 1);
    const int b = blockIdx.x >> 6;
    const int tok0 = b * T_ + c * L_;
    const int d0 = t * 4;
    const int buck = d0 >> 8;
    load_chunk_lds(Z, al_acc, E2b, tok0, t, Zs, als);

    float4 u[4][4];
#pragma unroll
    for (int j = 0; j < 4; j++)
#pragma unroll
        for (int q = 0; q < 4; q++)
            u[j][q] = *(const float4*)&Uw[(size_t)(d0 + j) * R_ + q * 4];
    float4 ab = *(const float4*)&a_base[d0];
    float4 td = *(const float4*)&tanhd[d0];
    float abv[4] = {ab.x, ab.y, ab.z, ab.w};
    float tdv[4] = {td.x, td.y, td.z, td.w};
    __syncthreads();

    float a[4] = {1.f, 1.f, 1.f, 1.f}, s[4] = {};
    for (int i = 0; i < L_; i++) {
        float av = als[i * 3 + buck];
#pragma unroll
        for (int j = 0; j < 4; j++) {
            float lam = sigmoidf_(fmaf(av, tdv[j], abv[j]));
            float bu  = dot16(&Zs[i * R_], u[j]);
            a[j] *= lam;
            s[j] = fmaf(lam, s[j], bu);
        }
    }
    size_t o = ((size_t)(b * NC_ + c)) * D_ + d0;
    *(float4*)&Aagg[o] = make_float4(a[0], a[1], a[2], a[3]);
    *(float4*)&Send[o] = make_float4(s[0], s[1], s[2], s[3]);
}

// pass3 with in-block carry computation (pass2 fused): the carry-in for
// chunk c is the prefix scan of Aagg/Send over chunks 0..c-1 (L2-resident,
// block-uniform trip count -> no divergence).
__global__ __launch_bounds__(192)
void scan_pass3(const float* __restrict__ Z, const float* __restrict__ al_acc,
                const float* __restrict__ E2b,
                const float* __restrict__ Uw, const float* __restrict__ a_base,
                const float* __restrict__ tanhd,
                const float* __restrict__ Aagg, const float* __restrict__ Send,
                unsigned short* __restrict__ Sout) {
    __shared__ float Zs[L_ * R_];
    __shared__ float als[L_ * 3];
    const int t = threadIdx.x;
    const int c = blockIdx.x & (NC_ - 1);
    const int b = blockIdx.x >> 6;
    const int tok0 = b * T_ + c * L_;
    const int d0 = t * 4;
    const int buck = d0 >> 8;
    load_chunk_lds(Z, al_acc, E2b, tok0, t, Zs, als);

    float4 u[4][4];
#pragma unroll
    for (int j = 0; j < 4; j++)
#pragma unroll
        for (int q = 0; q < 4; q++)
            u[j][q] = *(const float4*)&Uw[(size_t)(d0 + j) * R_ + q * 4];
    float4 ab = *(const float4*)&a_base[d0];
    float4 td = *(const float4*)&tanhd[d0];
    float abv[4] = {ab.x, ab.y, ab.z, ab.w};
    float tdv[4] = {td.x, td.y, td.z, td.w};

    // carry-in: prefix over earlier chunks (pass2 fused in)
    float s[4] = {0.f, 0.f, 0.f, 0.f};
#pragma unroll 4
    for (int cc = 0; cc < c; ++cc) {
        size_t o = ((size_t)(b * NC_ + cc)) * D_ + d0;
        float4 a4 = *(const float4*)&Aagg[o];
        float4 s4 = *(const float4*)&Send[o];
        s[0] = fmaf(a4.x, s[0], s4.x);
        s[1] = fmaf(a4.y, s[1], s4.y);
        s[2] = fmaf(a4.z, s[2], s4.z);
        s[3] = fmaf(a4.w, s[3], s4.w);
    }
    __syncthreads();

    for (int i = 0; i < L_; i++) {
        float av = als[i * 3 + buck];
#pragma unroll
        for (int j = 0; j < 4; j++) {
            float lam = sigmoidf_(fmaf(av, tdv[j], abv[j]));
            float bu  = dot16(&Zs[i * R_], u[j]);
            s[j] = fmaf(lam, s[j], bu);
        }
        *(ushort4*)&Sout[(size_t)(tok0 + i) * D_ + d0] =
            make_ushort4(f2bf(s[0]), f2bf(s[1]), f2bf(s[2]), f2bf(s[3]));
    }
}

// ---------------------------------------------------------------------------
extern "C" void kernel_launch(void* const* d_in, const int* in_sizes, int n_in,
                              void* d_out, int out_size, void* d_ws, size_t ws_size,
                              hipStream_t stream) {
    const float* x       = (const float*)d_in[0];
    const float* V_w     = (const float*)d_in[1];
    const float* U_w     = (const float*)d_in[2];
    const float* E1_w    = (const float*)d_in[3];
    const float* E1_b    = (const float*)d_in[4];
    const float* E2_w    = (const float*)d_in[5];
    const float* E2_b    = (const float*)d_in[6];
    const float* a_base  = (const float*)d_in[7];
    const float* a_delta = (const float*)d_in[8];
    const float* C_w     = (const float*)d_in[9];
    const float* G_w     = (const float*)d_in[10];
    const float* G_b     = (const float*)d_in[11];
    float* out = (float*)d_out;

    // workspace layout
    char* p = (char*)d_ws;
    float* Aagg   = (float*)p;          p += (size_t)B_ * NC_ * D_ * 4;
    float* Send   = (float*)p;          p += (size_t)B_ * NC_ * D_ * 4;
    float* tanhd  = (float*)p;          p += (size_t)D_ * 4;
    float* Z      = (float*)p;          p += (size_t)N_ * R_ * 4;
    float* al_acc = (float*)p;          p += (size_t)N_ * 3 * 4;
    unsigned short* x_bf  = (unsigned short*)p; p += (size_t)N_ * D_ * 2;
    unsigned short* S_bf  = (unsigned short*)p; p += (size_t)N_ * D_ * 2;
    unsigned short* E1_bf = (unsigned short*)p; p += (size_t)DB_ * D_ * 2;
    unsigned short* Cw_bf = (unsigned short*)p; p += (size_t)D_ * D_ * 2;
    unsigned short* Gw_bf = (unsigned short*)p; p += (size_t)D_ * D_ * 2;

    // merged setup (weights cvt + zero + tanh) — one launch
    setup_all<<<(SEG_TOT + 255) / 256, 256, 0, stream>>>(
        E1_w, C_w, G_w, a_delta, E1_bf, Cw_bf, Gw_bf, al_acc, tanhd);

    // x -> bf16 and Z = x@V^T in one pass
    cvtz_kernel<<<N_ / 64, 256, 0, stream>>>(x, V_w, x_bf, Z);

    // E1 GEMM with fused alpha partials (H never materialized)
    gemm_e1_alpha<<<256, 512, 0, stream>>>(x_bf, E1_bf, E1_b, E2_w, al_acc);

    scan_pass1<<<B_ * NC_, 192, 0, stream>>>(Z, al_acc, E2_b, U_w, a_base, tanhd, Aagg, Send);
    scan_pass3<<<B_ * NC_, 192, 0, stream>>>(Z, al_acc, E2_b, U_w, a_base, tanhd, Aagg, Send, S_bf);

    gemm_fused_out<<<768, 512, 0, stream>>>(x_bf, Gw_bf, S_bf, Cw_bf, G_b, out);
}

// Round 12
// 281.077 us; speedup vs baseline: 1.4377x; 1.0340x over previous
//
#include <hip/hip_runtime.h>
#include <hip/hip_bf16.h>
#include <math.h>

// Problem constants
#define B_   8
#define T_   4096
#define D_   768
#define R_   16
#define DB_  256
#define N_   (B_ * T_)      // 32768 tokens
#define NC_  64             // scan chunks per sequence
#define L_   (T_ / NC_)     // 64 steps per chunk
#define NKS_ (D_ / 32)      // 24 K-steps of 32
#define BUF_  12288         // fused pipeline buffer: A 256x32 + B 128x32 (elems)
#define BUFE_ 8192          // e1 pipeline buffer:    A 128x32 + B 128x32 (elems)

typedef __attribute__((ext_vector_type(8))) short bf16x8;
typedef __attribute__((ext_vector_type(4))) float f32x4;

__device__ __forceinline__ float gelu_exact(float x) {
    return 0.5f * x * (1.0f + erff(x * 0.70710678118654752f));
}
__device__ __forceinline__ float sigmoidf_(float x) {
    return 1.0f / (1.0f + expf(-x));
}
__device__ __forceinline__ float bf2f(unsigned short u) {
    return __uint_as_float(((unsigned)u) << 16);
}
__device__ __forceinline__ unsigned short f2bf(float f) {
    __hip_bfloat16 h = __float2bfloat16(f);   // RNE
    return *(unsigned short*)&h;
}
__device__ __forceinline__ bf16x8 pack8(float4 a, float4 b) {
    bf16x8 r;
    r[0] = (short)f2bf(a.x); r[1] = (short)f2bf(a.y);
    r[2] = (short)f2bf(a.z); r[3] = (short)f2bf(a.w);
    r[4] = (short)f2bf(b.x); r[5] = (short)f2bf(b.y);
    r[6] = (short)f2bf(b.z); r[7] = (short)f2bf(b.w);
    return r;
}

// async global->LDS, 16B per lane. LDS dest = wave-uniform base + lane*16.
__device__ __forceinline__ void gload16(const unsigned short* g, unsigned short* l) {
    __builtin_amdgcn_global_load_lds(
        (const __attribute__((address_space(1))) unsigned int*)(const void*)g,
        (__attribute__((address_space(3))) unsigned int*)(void*)l,
        16, 0, 0);
}

// swizzled LDS fragment read: 8 bf16 for mfma_16x16x32 (bank-conflict-free;
// source quad was pre-swizzled with the same q ^= (row>>1)&3 — rule 21)
__device__ __forceinline__ bf16x8 frag_read(const unsigned short* lds, int row, int lq) {
    int q = lq ^ ((row >> 1) & 3);
    return *(const bf16x8*)(lds + row * 32 + q * 8);
}

// chunked XCD swizzle (nwg % 8 == 0), then col-fastest decode
__device__ __forceinline__ void tile_decode(int nwg, int ncol, int& rowt, int& colt) {
    int bid = blockIdx.x;
    int cpx = nwg >> 3;
    int swz = (bid & 7) * cpx + (bid >> 3);
    colt = swz % ncol;
    rowt = swz / ncol;
}

// ===========================================================================
// FUSED variant (proven 123.5us): 512 threads, block 256x128,
// wave tile 64x64 (wave grid 4x2). Loads/thread/K-step = 3; vmcnt(3).
// ===========================================================================
__device__ __forceinline__ void stage_a(const unsigned short* src, int row0, int k0,
                                        unsigned short* lds, int w, int l) {
#pragma unroll
    for (int j = 0; j < 2; ++j) {
        int i = ((w * 2 + j) << 6) + l;     // 0..1023 (256 rows x 4 quads)
        int row = i >> 2, q = i & 3;
        int qs = q ^ ((row >> 1) & 3);
        gload16(src + (size_t)(row0 + row) * D_ + k0 + qs * 8, lds + ((w * 2 + j) << 9));
    }
}
__device__ __forceinline__ void stage_b(const unsigned short* src, int col0, int k0,
                                        unsigned short* lds, int w, int l) {
    int i = (w << 6) + l;                   // 0..511 (128 rows x 4 quads)
    int row = i >> 2, q = i & 3;
    int qs = q ^ ((row >> 1) & 3);
    gload16(src + (size_t)(col0 + row) * D_ + k0 + qs * 8, lds + (w << 9));
}

__device__ __forceinline__ void tile_mfma44(const unsigned short* la, const unsigned short* lb,
                                            int wrow, int wcol, int lr, int lq,
                                            f32x4 acc[4][4]) {
    bf16x8 a[4], b[4];
#pragma unroll
    for (int m = 0; m < 4; m++) a[m] = frag_read(la, wrow + m * 16 + lr, lq);
#pragma unroll
    for (int n = 0; n < 4; n++) b[n] = frag_read(lb, wcol + n * 16 + lr, lq);
    __builtin_amdgcn_s_setprio(1);
#pragma unroll
    for (int m = 0; m < 4; m++)
#pragma unroll
        for (int n = 0; n < 4; n++)
            acc[m][n] = __builtin_amdgcn_mfma_f32_16x16x32_bf16(a[m], b[n], acc[m][n], 0, 0, 0);
    __builtin_amdgcn_s_setprio(0);
}

__device__ __forceinline__ void prologueF(const unsigned short* __restrict__ A,
                                          const unsigned short* __restrict__ Bm,
                                          int row0, int col0,
                                          unsigned short* lds, int w, int l) {
    stage_a(A,  row0, 0,  lds,                w, l);
    stage_b(Bm, col0, 0,  lds + 8192,         w, l);
    stage_a(A,  row0, 32, lds + BUF_,         w, l);
    stage_b(Bm, col0, 32, lds + BUF_ + 8192,  w, l);
}

template <bool DO_PROLOGUE>
__device__ __forceinline__ void kloopF(const unsigned short* __restrict__ A,
                                       const unsigned short* __restrict__ Bm,
                                       int row0, int col0,
                                       unsigned short* lds,   // 3 * BUF_
                                       int w, int l, f32x4 acc[4][4]) {
    const int lr = l & 15, lq = l >> 4;
    const int wrow = (w >> 1) * 64, wcol = (w & 1) * 64;

    if (DO_PROLOGUE) prologueF(A, Bm, row0, col0, lds, w, l);

#pragma unroll 3
    for (int t = 0; t < NKS_ - 2; ++t) {
        asm volatile("s_waitcnt vmcnt(3)" ::: "memory");
        __builtin_amdgcn_s_barrier();
        __builtin_amdgcn_sched_barrier(0);
        unsigned short* bn = lds + ((t + 2) % 3) * BUF_;
        stage_a(A,  row0, (t + 2) * 32, bn,        w, l);
        stage_b(Bm, col0, (t + 2) * 32, bn + 8192, w, l);
        unsigned short* bc = lds + (t % 3) * BUF_;
        tile_mfma44(bc, bc + 8192, wrow, wcol, lr, lq, acc);
    }
    asm volatile("s_waitcnt vmcnt(3)" ::: "memory");
    __builtin_amdgcn_s_barrier();
    __builtin_amdgcn_sched_barrier(0);
    {
        unsigned short* bc = lds + ((NKS_ - 2) % 3) * BUF_;
        tile_mfma44(bc, bc + 8192, wrow, wcol, lr, lq, acc);
    }
    asm volatile("s_waitcnt vmcnt(0)" ::: "memory");
    __builtin_amdgcn_s_barrier();
    __builtin_amdgcn_sched_barrier(0);
    {
        unsigned short* bc = lds + ((NKS_ - 1) % 3) * BUF_;
        tile_mfma44(bc, bc + 8192, wrow, wcol, lr, lq, acc);
    }
}

// ---------------------------------------------------------------------------
// Fused: gate = sigmoid(Xb@G^T+Gb) (packed bf16 in regs), then
//        out = x_bf + gelu(Sb@C^T) * gate.
// Block 256x128, 512 thr, grid 768 (6 col x 128 row), 2 blocks/CU. [proven]
// ---------------------------------------------------------------------------
__global__ __launch_bounds__(512, 2)
void gemm_fused_out(const unsigned short* __restrict__ Xb,
                    const unsigned short* __restrict__ Gwb,
                    const unsigned short* __restrict__ Sb,
                    const unsigned short* __restrict__ Cwb,
                    const float* __restrict__ Gbias,
                    float* __restrict__ out) {
    __shared__ unsigned short lds[3 * BUF_];
    const int t = threadIdx.x, l = t & 63, w = t >> 6;
    int rowt, colt;
    tile_decode(768, 6, rowt, colt);
    const int row0 = rowt * 256, col0 = colt * 128;
    const int lr = l & 15, lq = l >> 4;
    const int wrow = (w >> 1) * 64, wcol = (w & 1) * 64;

    // hoist Gbias so the gate pack is pure VALU (vmcnt stream stays clean)
    float gb[4];
#pragma unroll
    for (int n = 0; n < 4; n++) gb[n] = Gbias[col0 + wcol + n * 16 + lr];

    f32x4 acc[4][4] = {};
    kloopF<true>(Xb, Gwb, row0, col0, lds, w, l, acc);

    // issue kloop-C prologue now: HBM latency hides under the gate pack.
    // Safe: all buffer readers passed the final kloop-G barriers.
    prologueF(Sb, Cwb, row0, col0, lds, w, l);

    unsigned int gp[4][4][2];
#pragma unroll
    for (int m = 0; m < 4; m++)
#pragma unroll
        for (int n = 0; n < 4; n++) {
            gp[m][n][0] = (unsigned)f2bf(sigmoidf_(acc[m][n][0] + gb[n]))
                        | ((unsigned)f2bf(sigmoidf_(acc[m][n][1] + gb[n])) << 16);
            gp[m][n][1] = (unsigned)f2bf(sigmoidf_(acc[m][n][2] + gb[n]))
                        | ((unsigned)f2bf(sigmoidf_(acc[m][n][3] + gb[n])) << 16);
            acc[m][n] = (f32x4){0.f, 0.f, 0.f, 0.f};
        }

    kloopF<false>(Sb, Cwb, row0, col0, lds, w, l, acc);

#pragma unroll
    for (int m = 0; m < 4; m++)
#pragma unroll
        for (int n = 0; n < 4; n++) {
            int col = col0 + wcol + n * 16 + lr;
#pragma unroll
            for (int r = 0; r < 4; r++) {
                int row = row0 + wrow + m * 16 + lq * 4 + r;
                size_t o = (size_t)row * D_ + col;
                float g = bf2f((unsigned short)(gp[m][n][r >> 1] >> ((r & 1) * 16)));
                out[o] = bf2f(Xb[o]) + gelu_exact(acc[m][n][r]) * g;
            }
        }
}

// ===========================================================================
// E1 variant (full-chip): 512 threads, block 128x128, wave grid 4x2,
// wave tile 32x64, acc[2][4]. Loads/thread/K-step = 2; vmcnt(2).
// grid 512 = 2 blocks/CU on all 256 CUs. LDS 3 x 16KB = 48KB.
// ===========================================================================
__device__ __forceinline__ void stage_e(const unsigned short* __restrict__ A,
                                        const unsigned short* __restrict__ Bm,
                                        int row0, int col0, int k0,
                                        unsigned short* buf, int w, int l) {
    int i = (w << 6) + l;                   // 0..511 (128 rows x 4 quads)
    int row = i >> 2, q = i & 3;
    int qs = q ^ ((row >> 1) & 3);
    gload16(A  + (size_t)(row0 + row) * D_ + k0 + qs * 8, buf + (w << 9));
    gload16(Bm + (size_t)(col0 + row) * D_ + k0 + qs * 8, buf + 4096 + (w << 9));
}

__device__ __forceinline__ void tile_mfma24(const unsigned short* buf,
                                            int wrow, int wcol, int lr, int lq,
                                            f32x4 acc[2][4]) {
    const unsigned short* la = buf;
    const unsigned short* lb = buf + 4096;
    bf16x8 a[2], b[4];
#pragma unroll
    for (int m = 0; m < 2; m++) a[m] = frag_read(la, wrow + m * 16 + lr, lq);
#pragma unroll
    for (int n = 0; n < 4; n++) b[n] = frag_read(lb, wcol + n * 16 + lr, lq);
    __builtin_amdgcn_s_setprio(1);
#pragma unroll
    for (int m = 0; m < 2; m++)
#pragma unroll
        for (int n = 0; n < 4; n++)
            acc[m][n] = __builtin_amdgcn_mfma_f32_16x16x32_bf16(a[m], b[n], acc[m][n], 0, 0, 0);
    __builtin_amdgcn_s_setprio(0);
}

__device__ __forceinline__ void kloopE(const unsigned short* __restrict__ A,
                                       const unsigned short* __restrict__ Bm,
                                       int row0, int col0,
                                       unsigned short* lds,   // 3 * BUFE_
                                       int w, int l, f32x4 acc[2][4]) {
    const int lr = l & 15, lq = l >> 4;
    const int wrow = (w >> 1) * 32, wcol = (w & 1) * 64;

    stage_e(A, Bm, row0, col0, 0,  lds,         w, l);
    stage_e(A, Bm, row0, col0, 32, lds + BUFE_, w, l);

#pragma unroll 3
    for (int t = 0; t < NKS_ - 2; ++t) {
        asm volatile("s_waitcnt vmcnt(2)" ::: "memory");
        __builtin_amdgcn_s_barrier();
        __builtin_amdgcn_sched_barrier(0);
        stage_e(A, Bm, row0, col0, (t + 2) * 32, lds + ((t + 2) % 3) * BUFE_, w, l);
        tile_mfma24(lds + (t % 3) * BUFE_, wrow, wcol, lr, lq, acc);
    }
    asm volatile("s_waitcnt vmcnt(2)" ::: "memory");
    __builtin_amdgcn_s_barrier();
    __builtin_amdgcn_sched_barrier(0);
    tile_mfma24(lds + ((NKS_ - 2) % 3) * BUFE_, wrow, wcol, lr, lq, acc);
    asm volatile("s_waitcnt vmcnt(0)" ::: "memory");
    __builtin_amdgcn_s_barrier();
    __builtin_amdgcn_sched_barrier(0);
    tile_mfma24(lds + ((NKS_ - 1) % 3) * BUFE_, wrow, wcol, lr, lq, acc);
}

// ---------------------------------------------------------------------------
// E1 GEMM + alpha partials (H never materialized). Block 128x128, 512 thr,
// grid 512 (2 col x 256 row) -> full chip at 2 blocks/CU.
// ---------------------------------------------------------------------------
__global__ __launch_bounds__(512, 2)
void gemm_e1_alpha(const unsigned short* __restrict__ Xb,
                   const unsigned short* __restrict__ Wb,
                   const float* __restrict__ bias,
                   const float* __restrict__ E2w,
                   float* __restrict__ alpha_acc) {
    __shared__ unsigned short lds[3 * BUFE_];
    const int t = threadIdx.x, l = t & 63, w = t >> 6;
    int rowt, colt;
    tile_decode(512, 2, rowt, colt);
    const int row0 = rowt * 128, col0 = colt * 128;
    const int lr = l & 15, lq = l >> 4;
    const int wrow = (w >> 1) * 32, wcol = (w & 1) * 64;
    f32x4 acc[2][4] = {};
    kloopE(Xb, Wb, row0, col0, lds, w, l, acc);

    float bia[4], e2v[3][4];
#pragma unroll
    for (int n = 0; n < 4; n++) {
        int col = col0 + wcol + n * 16 + lr;
        bia[n] = bias[col];
#pragma unroll
        for (int c = 0; c < 3; c++) e2v[c][n] = E2w[c * DB_ + col];
    }
#pragma unroll
    for (int m = 0; m < 2; m++)
#pragma unroll
        for (int r = 0; r < 4; r++) {
            float p0 = 0.f, p1 = 0.f, p2 = 0.f;
#pragma unroll
            for (int n = 0; n < 4; n++) {
                float h = gelu_exact(acc[m][n][r] + bia[n]);
                p0 = fmaf(h, e2v[0][n], p0);
                p1 = fmaf(h, e2v[1][n], p1);
                p2 = fmaf(h, e2v[2][n], p2);
            }
#pragma unroll
            for (int s = 1; s < 16; s <<= 1) {
                p0 += __shfl_xor(p0, s);
                p1 += __shfl_xor(p1, s);
                p2 += __shfl_xor(p2, s);
            }
            if (lr == 0) {
                int row = row0 + wrow + m * 16 + lq * 4 + r;
                atomicAdd(&alpha_acc[(size_t)row * 3 + 0], p0);
                atomicAdd(&alpha_acc[(size_t)row * 3 + 1], p1);
                atomicAdd(&alpha_acc[(size_t)row * 3 + 2], p2);
            }
        }
}

// ---------------------------------------------------------------------------
// Fused cvt + Z + setup: x_bf = bf16(x); Z = x_bf @ V^T; then a grid-stride
// tail converts E1/C/G weights, zeros al_acc, computes tanh(a_delta).
// One wave = 16 tokens; block = 4 waves = 64 tokens; grid 512.
// ---------------------------------------------------------------------------
#define SEG_E1  (DB_ * D_ / 4)             // 49152
#define SEG_W   (D_ * D_ / 4)              // 147456
#define SEG_Z   (N_ * 3 / 4)               // 24576
#define SEG_TOT (SEG_E1 + 2 * SEG_W + SEG_Z + 192)

__global__ __launch_bounds__(256)
void cvtz_kernel(const float* __restrict__ X, const float* __restrict__ Vw,
                 unsigned short* __restrict__ Xb, float* __restrict__ Z,
                 const float* __restrict__ E1_w, const float* __restrict__ C_w,
                 const float* __restrict__ G_w, const float* __restrict__ a_delta,
                 unsigned short* __restrict__ E1b, unsigned short* __restrict__ Cwb,
                 unsigned short* __restrict__ Gwb, float* __restrict__ al_acc,
                 float* __restrict__ tanhd) {
    const int t = threadIdx.x, l = t & 63, w = t >> 6;
    const int lr = l & 15, lq = l >> 4;
    const int tok0 = (blockIdx.x * 4 + w) * 16;
    const float* xrow = X  + (size_t)(tok0 + lr) * D_;
    const float* vrow = Vw + (size_t)lr * D_;
    f32x4 acc = {};
#pragma unroll 4
    for (int k0 = 0; k0 < D_; k0 += 32) {
        int k = k0 + lq * 8;
        float4 xa = *(const float4*)&xrow[k];
        float4 xb = *(const float4*)&xrow[k + 4];
        float4 va = *(const float4*)&vrow[k];
        float4 vb = *(const float4*)&vrow[k + 4];
        bf16x8 xf = pack8(xa, xb);
        bf16x8 vf = pack8(va, vb);
        *(bf16x8*)&Xb[(size_t)(tok0 + lr) * D_ + k] = xf;
        acc = __builtin_amdgcn_mfma_f32_16x16x32_bf16(xf, vf, acc, 0, 0, 0);
    }
#pragma unroll
    for (int rr = 0; rr < 4; rr++)
        Z[(size_t)(tok0 + lq * 4 + rr) * R_ + lr] = acc[rr];

    // setup tail (grid-stride over segment-decoded float4 items)
    for (int i = blockIdx.x * 256 + t; i < SEG_TOT; i += 512 * 256) {
        if (i < SEG_E1) {
            float4 v = ((const float4*)E1_w)[i];
            ((ushort4*)E1b)[i] = make_ushort4(f2bf(v.x), f2bf(v.y), f2bf(v.z), f2bf(v.w));
        } else if (i < SEG_E1 + SEG_W) {
            int j = i - SEG_E1;
            float4 v = ((const float4*)C_w)[j];
            ((ushort4*)Cwb)[j] = make_ushort4(f2bf(v.x), f2bf(v.y), f2bf(v.z), f2bf(v.w));
        } else if (i < SEG_E1 + 2 * SEG_W) {
            int j = i - SEG_E1 - SEG_W;
            float4 v = ((const float4*)G_w)[j];
            ((ushort4*)Gwb)[j] = make_ushort4(f2bf(v.x), f2bf(v.y), f2bf(v.z), f2bf(v.w));
        } else if (i < SEG_E1 + 2 * SEG_W + SEG_Z) {
            int j = i - SEG_E1 - 2 * SEG_W;
            ((float4*)al_acc)[j] = make_float4(0.f, 0.f, 0.f, 0.f);
        } else {
            int j = (i - SEG_E1 - 2 * SEG_W - SEG_Z) * 4;
            tanhd[j + 0] = tanhf(a_delta[j + 0]);
            tanhd[j + 1] = tanhf(a_delta[j + 1]);
            tanhd[j + 2] = tanhf(a_delta[j + 2]);
            tanhd[j + 3] = tanhf(a_delta[j + 3]);
        }
    }
}

// ---------------------------------------------------------------------------
// Scan with on-the-fly lam/bu recompute; alpha finalized inline.
// ---------------------------------------------------------------------------
__device__ __forceinline__ void load_chunk_lds(const float* __restrict__ Z,
                                               const float* __restrict__ al_acc,
                                               const float* __restrict__ E2b,
                                               int tok0, int t,
                                               float* Zs, float* als) {
#pragma unroll
    for (int i = t; i < L_ * R_ / 4; i += 192)
        *(float4*)&Zs[i * 4] = *(const float4*)&Z[(size_t)tok0 * R_ + i * 4];
    als[t] = sigmoidf_(al_acc[(size_t)tok0 * 3 + t] + E2b[t % 3]);   // 192 = 64*3
}

__device__ __forceinline__ float dot16(const float* zrow, const float4* u) {
    float4 z0 = *(const float4*)&zrow[0],  z1 = *(const float4*)&zrow[4];
    float4 z2 = *(const float4*)&zrow[8],  z3 = *(const float4*)&zrow[12];
    return z0.x*u[0].x + z0.y*u[0].y + z0.z*u[0].z + z0.w*u[0].w
         + z1.x*u[1].x + z1.y*u[1].y + z1.z*u[1].z + z1.w*u[1].w
         + z2.x*u[2].x + z2.y*u[2].y + z2.z*u[2].z + z2.w*u[2].w
         + z3.x*u[3].x + z3.y*u[3].y + z3.z*u[3].z + z3.w*u[3].w;
}

__global__ __launch_bounds__(192)
void scan_pass1(const float* __restrict__ Z, const float* __restrict__ al_acc,
                const float* __restrict__ E2b,
                const float* __restrict__ Uw, const float* __restrict__ a_base,
                const float* __restrict__ tanhd,
                float* __restrict__ Aagg, float* __restrict__ Send) {
    __shared__ float Zs[L_ * R_];
    __shared__ float als[L_ * 3];
    const int t = threadIdx.x;
    const int c = blockIdx.x & (NC_ - 1);
    const int b = blockIdx.x >> 6;
    const int tok0 = b * T_ + c * L_;
    const int d0 = t * 4;
    const int buck = d0 >> 8;
    load_chunk_lds(Z, al_acc, E2b, tok0, t, Zs, als);

    float4 u[4][4];
#pragma unroll
    for (int j = 0; j < 4; j++)
#pragma unroll
        for (int q = 0; q < 4; q++)
            u[j][q] = *(const float4*)&Uw[(size_t)(d0 + j) * R_ + q * 4];
    float4 ab = *(const float4*)&a_base[d0];
    float4 td = *(const float4*)&tanhd[d0];
    float abv[4] = {ab.x, ab.y, ab.z, ab.w};
    float tdv[4] = {td.x, td.y, td.z, td.w};
    __syncthreads();

    float a[4] = {1.f, 1.f, 1.f, 1.f}, s[4] = {};
    for (int i = 0; i < L_; i++) {
        float av = als[i * 3 + buck];
#pragma unroll
        for (int j = 0; j < 4; j++) {
            float lam = sigmoidf_(fmaf(av, tdv[j], abv[j]));
            float bu  = dot16(&Zs[i * R_], u[j]);
            a[j] *= lam;
            s[j] = fmaf(lam, s[j], bu);
        }
    }
    size_t o = ((size_t)(b * NC_ + c)) * D_ + d0;
    *(float4*)&Aagg[o] = make_float4(a[0], a[1], a[2], a[3]);
    *(float4*)&Send[o] = make_float4(s[0], s[1], s[2], s[3]);
}

// pass3 with in-block carry computation (pass2 fused): the carry-in for
// chunk c is the prefix scan of Aagg/Send over chunks 0..c-1 (L2-resident,
// block-uniform trip count -> no divergence).
__global__ __launch_bounds__(192)
void scan_pass3(const float* __restrict__ Z, const float* __restrict__ al_acc,
                const float* __restrict__ E2b,
                const float* __restrict__ Uw, const float* __restrict__ a_base,
                const float* __restrict__ tanhd,
                const float* __restrict__ Aagg, const float* __restrict__ Send,
                unsigned short* __restrict__ Sout) {
    __shared__ float Zs[L_ * R_];
    __shared__ float als[L_ * 3];
    const int t = threadIdx.x;
    const int c = blockIdx.x & (NC_ - 1);
    const int b = blockIdx.x >> 6;
    const int tok0 = b * T_ + c * L_;
    const int d0 = t * 4;
    const int buck = d0 >> 8;
    load_chunk_lds(Z, al_acc, E2b, tok0, t, Zs, als);

    float4 u[4][4];
#pragma unroll
    for (int j = 0; j < 4; j++)
#pragma unroll
        for (int q = 0; q < 4; q++)
            u[j][q] = *(const float4*)&Uw[(size_t)(d0 + j) * R_ + q * 4];
    float4 ab = *(const float4*)&a_base[d0];
    float4 td = *(const float4*)&tanhd[d0];
    float abv[4] = {ab.x, ab.y, ab.z, ab.w};
    float tdv[4] = {td.x, td.y, td.z, td.w};

    // carry-in: prefix over earlier chunks (pass2 fused in)
    float s[4] = {0.f, 0.f, 0.f, 0.f};
#pragma unroll 4
    for (int cc = 0; cc < c; ++cc) {
        size_t o = ((size_t)(b * NC_ + cc)) * D_ + d0;
        float4 a4 = *(const float4*)&Aagg[o];
        float4 s4 = *(const float4*)&Send[o];
        s[0] = fmaf(a4.x, s[0], s4.x);
        s[1] = fmaf(a4.y, s[1], s4.y);
        s[2] = fmaf(a4.z, s[2], s4.z);
        s[3] = fmaf(a4.w, s[3], s4.w);
    }
    __syncthreads();

    for (int i = 0; i < L_; i++) {
        float av = als[i * 3 + buck];
#pragma unroll
        for (int j = 0; j < 4; j++) {
            float lam = sigmoidf_(fmaf(av, tdv[j], abv[j]));
            float bu  = dot16(&Zs[i * R_], u[j]);
            s[j] = fmaf(lam, s[j], bu);
        }
        *(ushort4*)&Sout[(size_t)(tok0 + i) * D_ + d0] =
            make_ushort4(f2bf(s[0]), f2bf(s[1]), f2bf(s[2]), f2bf(s[3]));
    }
}

// ---------------------------------------------------------------------------
extern "C" void kernel_launch(void* const* d_in, const int* in_sizes, int n_in,
                              void* d_out, int out_size, void* d_ws, size_t ws_size,
                              hipStream_t stream) {
    const float* x       = (const float*)d_in[0];
    const float* V_w     = (const float*)d_in[1];
    const float* U_w     = (const float*)d_in[2];
    const float* E1_w    = (const float*)d_in[3];
    const float* E1_b    = (const float*)d_in[4];
    const float* E2_w    = (const float*)d_in[5];
    const float* E2_b    = (const float*)d_in[6];
    const float* a_base  = (const float*)d_in[7];
    const float* a_delta = (const float*)d_in[8];
    const float* C_w     = (const float*)d_in[9];
    const float* G_w     = (const float*)d_in[10];
    const float* G_b     = (const float*)d_in[11];
    float* out = (float*)d_out;

    // workspace layout
    char* p = (char*)d_ws;
    float* Aagg   = (float*)p;          p += (size_t)B_ * NC_ * D_ * 4;
    float* Send   = (float*)p;          p += (size_t)B_ * NC_ * D_ * 4;
    float* tanhd  = (float*)p;          p += (size_t)D_ * 4;
    float* Z      = (float*)p;          p += (size_t)N_ * R_ * 4;
    float* al_acc = (float*)p;          p += (size_t)N_ * 3 * 4;
    unsigned short* x_bf  = (unsigned short*)p; p += (size_t)N_ * D_ * 2;
    unsigned short* S_bf  = (unsigned short*)p; p += (size_t)N_ * D_ * 2;
    unsigned short* E1_bf = (unsigned short*)p; p += (size_t)DB_ * D_ * 2;
    unsigned short* Cw_bf = (unsigned short*)p; p += (size_t)D_ * D_ * 2;
    unsigned short* Gw_bf = (unsigned short*)p; p += (size_t)D_ * D_ * 2;

    // x -> bf16, Z = x@V^T, and all setup work in one launch
    cvtz_kernel<<<N_ / 64, 256, 0, stream>>>(x, V_w, x_bf, Z,
                                             E1_w, C_w, G_w, a_delta,
                                             E1_bf, Cw_bf, Gw_bf, al_acc, tanhd);

    // E1 GEMM with fused alpha partials (H never materialized), full chip
    gemm_e1_alpha<<<512, 512, 0, stream>>>(x_bf, E1_bf, E1_b, E2_w, al_acc);

    scan_pass1<<<B_ * NC_, 192, 0, stream>>>(Z, al_acc, E2_b, U_w, a_base, tanhd, Aagg, Send);
    scan_pass3<<<B_ * NC_, 192, 0, stream>>>(Z, al_acc, E2_b, U_w, a_base, tanhd, Aagg, Send, S_bf);

    gemm_fused_out<<<768, 512, 0, stream>>>(x_bf, Gw_bf, S_bf, Cw_bf, G_b, out);
}

// Round 13
// 275.394 us; speedup vs baseline: 1.4674x; 1.0206x over previous
//
#include <hip/hip_runtime.h>
#include <hip/hip_bf16.h>
#include <math.h>

// Problem constants
#define B_   8
#define T_   4096
#define D_   768
#define R_   16
#define DB_  256
#define N_   (B_ * T_)      // 32768 tokens
#define NC_  64             // scan chunks per sequence
#define L_   (T_ / NC_)     // 64 steps per chunk
#define NKS_ (D_ / 32)      // 24 K-steps of 32
#define BUF_  12288         // fused pipeline buffer: A 256x32 + B 128x32 (elems)
#define BUFE_ 8192          // e1 pipeline buffer:    A 128x32 + B 128x32 (elems)

typedef __attribute__((ext_vector_type(8))) short bf16x8;
typedef __attribute__((ext_vector_type(4))) float f32x4;

__device__ __forceinline__ float gelu_exact(float x) {
    return 0.5f * x * (1.0f + erff(x * 0.70710678118654752f));
}
__device__ __forceinline__ float sigmoidf_(float x) {
    return 1.0f / (1.0f + expf(-x));
}
__device__ __forceinline__ float bf2f(unsigned short u) {
    return __uint_as_float(((unsigned)u) << 16);
}
__device__ __forceinline__ unsigned short f2bf(float f) {
    __hip_bfloat16 h = __float2bfloat16(f);   // RNE
    return *(unsigned short*)&h;
}
__device__ __forceinline__ bf16x8 pack8(float4 a, float4 b) {
    bf16x8 r;
    r[0] = (short)f2bf(a.x); r[1] = (short)f2bf(a.y);
    r[2] = (short)f2bf(a.z); r[3] = (short)f2bf(a.w);
    r[4] = (short)f2bf(b.x); r[5] = (short)f2bf(b.y);
    r[6] = (short)f2bf(b.z); r[7] = (short)f2bf(b.w);
    return r;
}

// async global->LDS, 16B per lane. LDS dest = wave-uniform base + lane*16.
__device__ __forceinline__ void gload16(const unsigned short* g, unsigned short* l) {
    __builtin_amdgcn_global_load_lds(
        (const __attribute__((address_space(1))) unsigned int*)(const void*)g,
        (__attribute__((address_space(3))) unsigned int*)(void*)l,
        16, 0, 0);
}

// swizzled LDS fragment read: 8 bf16 for mfma_16x16x32 (bank-conflict-free;
// source quad was pre-swizzled with the same q ^= (row>>1)&3 — rule 21)
__device__ __forceinline__ bf16x8 frag_read(const unsigned short* lds, int row, int lq) {
    int q = lq ^ ((row >> 1) & 3);
    return *(const bf16x8*)(lds + row * 32 + q * 8);
}

// chunked XCD swizzle (nwg % 8 == 0), then col-fastest decode
__device__ __forceinline__ void tile_decode(int nwg, int ncol, int& rowt, int& colt) {
    int bid = blockIdx.x;
    int cpx = nwg >> 3;
    int swz = (bid & 7) * cpx + (bid >> 3);
    colt = swz % ncol;
    rowt = swz / ncol;
}

// ===========================================================================
// FUSED variant (proven 123.5us): 512 threads, block 256x128,
// wave tile 64x64 (wave grid 4x2). Loads/thread/K-step = 3; vmcnt(3).
// ===========================================================================
__device__ __forceinline__ void stage_a(const unsigned short* src, int row0, int k0,
                                        unsigned short* lds, int w, int l) {
#pragma unroll
    for (int j = 0; j < 2; ++j) {
        int i = ((w * 2 + j) << 6) + l;     // 0..1023 (256 rows x 4 quads)
        int row = i >> 2, q = i & 3;
        int qs = q ^ ((row >> 1) & 3);
        gload16(src + (size_t)(row0 + row) * D_ + k0 + qs * 8, lds + ((w * 2 + j) << 9));
    }
}
__device__ __forceinline__ void stage_b(const unsigned short* src, int col0, int k0,
                                        unsigned short* lds, int w, int l) {
    int i = (w << 6) + l;                   // 0..511 (128 rows x 4 quads)
    int row = i >> 2, q = i & 3;
    int qs = q ^ ((row >> 1) & 3);
    gload16(src + (size_t)(col0 + row) * D_ + k0 + qs * 8, lds + (w << 9));
}

__device__ __forceinline__ void tile_mfma44(const unsigned short* la, const unsigned short* lb,
                                            int wrow, int wcol, int lr, int lq,
                                            f32x4 acc[4][4]) {
    bf16x8 a[4], b[4];
#pragma unroll
    for (int m = 0; m < 4; m++) a[m] = frag_read(la, wrow + m * 16 + lr, lq);
#pragma unroll
    for (int n = 0; n < 4; n++) b[n] = frag_read(lb, wcol + n * 16 + lr, lq);
    __builtin_amdgcn_s_setprio(1);
#pragma unroll
    for (int m = 0; m < 4; m++)
#pragma unroll
        for (int n = 0; n < 4; n++)
            acc[m][n] = __builtin_amdgcn_mfma_f32_16x16x32_bf16(a[m], b[n], acc[m][n], 0, 0, 0);
    __builtin_amdgcn_s_setprio(0);
}

__device__ __forceinline__ void prologueF(const unsigned short* __restrict__ A,
                                          const unsigned short* __restrict__ Bm,
                                          int row0, int col0,
                                          unsigned short* lds, int w, int l) {
    stage_a(A,  row0, 0,  lds,                w, l);
    stage_b(Bm, col0, 0,  lds + 8192,         w, l);
    stage_a(A,  row0, 32, lds + BUF_,         w, l);
    stage_b(Bm, col0, 32, lds + BUF_ + 8192,  w, l);
}

template <bool DO_PROLOGUE>
__device__ __forceinline__ void kloopF(const unsigned short* __restrict__ A,
                                       const unsigned short* __restrict__ Bm,
                                       int row0, int col0,
                                       unsigned short* lds,   // 3 * BUF_
                                       int w, int l, f32x4 acc[4][4]) {
    const int lr = l & 15, lq = l >> 4;
    const int wrow = (w >> 1) * 64, wcol = (w & 1) * 64;

    if (DO_PROLOGUE) prologueF(A, Bm, row0, col0, lds, w, l);

#pragma unroll 3
    for (int t = 0; t < NKS_ - 2; ++t) {
        asm volatile("s_waitcnt vmcnt(3)" ::: "memory");
        __builtin_amdgcn_s_barrier();
        __builtin_amdgcn_sched_barrier(0);
        unsigned short* bn = lds + ((t + 2) % 3) * BUF_;
        stage_a(A,  row0, (t + 2) * 32, bn,        w, l);
        stage_b(Bm, col0, (t + 2) * 32, bn + 8192, w, l);
        unsigned short* bc = lds + (t % 3) * BUF_;
        tile_mfma44(bc, bc + 8192, wrow, wcol, lr, lq, acc);
    }
    asm volatile("s_waitcnt vmcnt(3)" ::: "memory");
    __builtin_amdgcn_s_barrier();
    __builtin_amdgcn_sched_barrier(0);
    {
        unsigned short* bc = lds + ((NKS_ - 2) % 3) * BUF_;
        tile_mfma44(bc, bc + 8192, wrow, wcol, lr, lq, acc);
    }
    asm volatile("s_waitcnt vmcnt(0)" ::: "memory");
    __builtin_amdgcn_s_barrier();
    __builtin_amdgcn_sched_barrier(0);
    {
        unsigned short* bc = lds + ((NKS_ - 1) % 3) * BUF_;
        tile_mfma44(bc, bc + 8192, wrow, wcol, lr, lq, acc);
    }
}

// ---------------------------------------------------------------------------
// Fused: gate = sigmoid(Xb@G^T+Gb) (packed bf16 in regs), then
//        out = x_bf + gelu(Sb@C^T) * gate.
// Block 256x128, 512 thr, grid 768 (6 col x 128 row), 2 blocks/CU. [proven]
// ---------------------------------------------------------------------------
__global__ __launch_bounds__(512, 2)
void gemm_fused_out(const unsigned short* __restrict__ Xb,
                    const unsigned short* __restrict__ Gwb,
                    const unsigned short* __restrict__ Sb,
                    const unsigned short* __restrict__ Cwb,
                    const float* __restrict__ Gbias,
                    float* __restrict__ out) {
    __shared__ unsigned short lds[3 * BUF_];
    const int t = threadIdx.x, l = t & 63, w = t >> 6;
    int rowt, colt;
    tile_decode(768, 6, rowt, colt);
    const int row0 = rowt * 256, col0 = colt * 128;
    const int lr = l & 15, lq = l >> 4;
    const int wrow = (w >> 1) * 64, wcol = (w & 1) * 64;

    // hoist Gbias so the gate pack is pure VALU (vmcnt stream stays clean)
    float gb[4];
#pragma unroll
    for (int n = 0; n < 4; n++) gb[n] = Gbias[col0 + wcol + n * 16 + lr];

    f32x4 acc[4][4] = {};
    kloopF<true>(Xb, Gwb, row0, col0, lds, w, l, acc);

    // issue kloop-C prologue now: HBM latency hides under the gate pack.
    // Safe: all buffer readers passed the final kloop-G barriers.
    prologueF(Sb, Cwb, row0, col0, lds, w, l);

    unsigned int gp[4][4][2];
#pragma unroll
    for (int m = 0; m < 4; m++)
#pragma unroll
        for (int n = 0; n < 4; n++) {
            gp[m][n][0] = (unsigned)f2bf(sigmoidf_(acc[m][n][0] + gb[n]))
                        | ((unsigned)f2bf(sigmoidf_(acc[m][n][1] + gb[n])) << 16);
            gp[m][n][1] = (unsigned)f2bf(sigmoidf_(acc[m][n][2] + gb[n]))
                        | ((unsigned)f2bf(sigmoidf_(acc[m][n][3] + gb[n])) << 16);
            acc[m][n] = (f32x4){0.f, 0.f, 0.f, 0.f};
        }

    kloopF<false>(Sb, Cwb, row0, col0, lds, w, l, acc);

#pragma unroll
    for (int m = 0; m < 4; m++)
#pragma unroll
        for (int n = 0; n < 4; n++) {
            int col = col0 + wcol + n * 16 + lr;
#pragma unroll
            for (int r = 0; r < 4; r++) {
                int row = row0 + wrow + m * 16 + lq * 4 + r;
                size_t o = (size_t)row * D_ + col;
                float g = bf2f((unsigned short)(gp[m][n][r >> 1] >> ((r & 1) * 16)));
                out[o] = bf2f(Xb[o]) + gelu_exact(acc[m][n][r]) * g;
            }
        }
}

// ===========================================================================
// E1 variant (full-chip): 512 threads, block 128x128, wave grid 4x2,
// wave tile 32x64, acc[2][4]. Loads/thread/K-step = 2; vmcnt(2).
// grid 512 = 2 blocks/CU on all 256 CUs. LDS 3 x 16KB = 48KB.
// ===========================================================================
__device__ __forceinline__ void stage_e(const unsigned short* __restrict__ A,
                                        const unsigned short* __restrict__ Bm,
                                        int row0, int col0, int k0,
                                        unsigned short* buf, int w, int l) {
    int i = (w << 6) + l;                   // 0..511 (128 rows x 4 quads)
    int row = i >> 2, q = i & 3;
    int qs = q ^ ((row >> 1) & 3);
    gload16(A  + (size_t)(row0 + row) * D_ + k0 + qs * 8, buf + (w << 9));
    gload16(Bm + (size_t)(col0 + row) * D_ + k0 + qs * 8, buf + 4096 + (w << 9));
}

__device__ __forceinline__ void tile_mfma24(const unsigned short* buf,
                                            int wrow, int wcol, int lr, int lq,
                                            f32x4 acc[2][4]) {
    const unsigned short* la = buf;
    const unsigned short* lb = buf + 4096;
    bf16x8 a[2], b[4];
#pragma unroll
    for (int m = 0; m < 2; m++) a[m] = frag_read(la, wrow + m * 16 + lr, lq);
#pragma unroll
    for (int n = 0; n < 4; n++) b[n] = frag_read(lb, wcol + n * 16 + lr, lq);
    __builtin_amdgcn_s_setprio(1);
#pragma unroll
    for (int m = 0; m < 2; m++)
#pragma unroll
        for (int n = 0; n < 4; n++)
            acc[m][n] = __builtin_amdgcn_mfma_f32_16x16x32_bf16(a[m], b[n], acc[m][n], 0, 0, 0);
    __builtin_amdgcn_s_setprio(0);
}

__device__ __forceinline__ void kloopE(const unsigned short* __restrict__ A,
                                       const unsigned short* __restrict__ Bm,
                                       int row0, int col0,
                                       unsigned short* lds,   // 3 * BUFE_
                                       int w, int l, f32x4 acc[2][4]) {
    const int lr = l & 15, lq = l >> 4;
    const int wrow = (w >> 1) * 32, wcol = (w & 1) * 64;

    stage_e(A, Bm, row0, col0, 0,  lds,         w, l);
    stage_e(A, Bm, row0, col0, 32, lds + BUFE_, w, l);

#pragma unroll 3
    for (int t = 0; t < NKS_ - 2; ++t) {
        asm volatile("s_waitcnt vmcnt(2)" ::: "memory");
        __builtin_amdgcn_s_barrier();
        __builtin_amdgcn_sched_barrier(0);
        stage_e(A, Bm, row0, col0, (t + 2) * 32, lds + ((t + 2) % 3) * BUFE_, w, l);
        tile_mfma24(lds + (t % 3) * BUFE_, wrow, wcol, lr, lq, acc);
    }
    asm volatile("s_waitcnt vmcnt(2)" ::: "memory");
    __builtin_amdgcn_s_barrier();
    __builtin_amdgcn_sched_barrier(0);
    tile_mfma24(lds + ((NKS_ - 2) % 3) * BUFE_, wrow, wcol, lr, lq, acc);
    asm volatile("s_waitcnt vmcnt(0)" ::: "memory");
    __builtin_amdgcn_s_barrier();
    __builtin_amdgcn_sched_barrier(0);
    tile_mfma24(lds + ((NKS_ - 1) % 3) * BUFE_, wrow, wcol, lr, lq, acc);
}

// ---------------------------------------------------------------------------
// E1 GEMM + alpha partials (H never materialized). Block 128x128, 512 thr,
// grid 512 (2 col x 256 row) -> full chip at 2 blocks/CU.
// ---------------------------------------------------------------------------
__global__ __launch_bounds__(512, 2)
void gemm_e1_alpha(const unsigned short* __restrict__ Xb,
                   const unsigned short* __restrict__ Wb,
                   const float* __restrict__ bias,
                   const float* __restrict__ E2w,
                   float* __restrict__ alpha_acc) {
    __shared__ unsigned short lds[3 * BUFE_];
    const int t = threadIdx.x, l = t & 63, w = t >> 6;
    int rowt, colt;
    tile_decode(512, 2, rowt, colt);
    const int row0 = rowt * 128, col0 = colt * 128;
    const int lr = l & 15, lq = l >> 4;
    const int wrow = (w >> 1) * 32, wcol = (w & 1) * 64;
    f32x4 acc[2][4] = {};
    kloopE(Xb, Wb, row0, col0, lds, w, l, acc);

    float bia[4], e2v[3][4];
#pragma unroll
    for (int n = 0; n < 4; n++) {
        int col = col0 + wcol + n * 16 + lr;
        bia[n] = bias[col];
#pragma unroll
        for (int c = 0; c < 3; c++) e2v[c][n] = E2w[c * DB_ + col];
    }
#pragma unroll
    for (int m = 0; m < 2; m++)
#pragma unroll
        for (int r = 0; r < 4; r++) {
            float p0 = 0.f, p1 = 0.f, p2 = 0.f;
#pragma unroll
            for (int n = 0; n < 4; n++) {
                float h = gelu_exact(acc[m][n][r] + bia[n]);
                p0 = fmaf(h, e2v[0][n], p0);
                p1 = fmaf(h, e2v[1][n], p1);
                p2 = fmaf(h, e2v[2][n], p2);
            }
#pragma unroll
            for (int s = 1; s < 16; s <<= 1) {
                p0 += __shfl_xor(p0, s);
                p1 += __shfl_xor(p1, s);
                p2 += __shfl_xor(p2, s);
            }
            if (lr == 0) {
                int row = row0 + wrow + m * 16 + lq * 4 + r;
                atomicAdd(&alpha_acc[(size_t)row * 3 + 0], p0);
                atomicAdd(&alpha_acc[(size_t)row * 3 + 1], p1);
                atomicAdd(&alpha_acc[(size_t)row * 3 + 2], p2);
            }
        }
}

// ---------------------------------------------------------------------------
// Fused cvt + Z + setup: x_bf = bf16(x); Z = x_bf @ V^T; then a grid-stride
// tail converts E1/C/G weights, zeros al_acc, computes tanh(a_delta).
// One wave = 16 tokens; block = 4 waves = 64 tokens; grid 512.
// ---------------------------------------------------------------------------
#define SEG_E1  (DB_ * D_ / 4)             // 49152
#define SEG_W   (D_ * D_ / 4)              // 147456
#define SEG_Z   (N_ * 3 / 4)               // 24576
#define SEG_TOT (SEG_E1 + 2 * SEG_W + SEG_Z + 192)

__global__ __launch_bounds__(256)
void cvtz_kernel(const float* __restrict__ X, const float* __restrict__ Vw,
                 unsigned short* __restrict__ Xb, float* __restrict__ Z,
                 const float* __restrict__ E1_w, const float* __restrict__ C_w,
                 const float* __restrict__ G_w, const float* __restrict__ a_delta,
                 unsigned short* __restrict__ E1b, unsigned short* __restrict__ Cwb,
                 unsigned short* __restrict__ Gwb, float* __restrict__ al_acc,
                 float* __restrict__ tanhd) {
    const int t = threadIdx.x, l = t & 63, w = t >> 6;
    const int lr = l & 15, lq = l >> 4;
    const int tok0 = (blockIdx.x * 4 + w) * 16;
    const float* xrow = X  + (size_t)(tok0 + lr) * D_;
    const float* vrow = Vw + (size_t)lr * D_;
    f32x4 acc = {};
#pragma unroll 4
    for (int k0 = 0; k0 < D_; k0 += 32) {
        int k = k0 + lq * 8;
        float4 xa = *(const float4*)&xrow[k];
        float4 xb = *(const float4*)&xrow[k + 4];
        float4 va = *(const float4*)&vrow[k];
        float4 vb = *(const float4*)&vrow[k + 4];
        bf16x8 xf = pack8(xa, xb);
        bf16x8 vf = pack8(va, vb);
        *(bf16x8*)&Xb[(size_t)(tok0 + lr) * D_ + k] = xf;
        acc = __builtin_amdgcn_mfma_f32_16x16x32_bf16(xf, vf, acc, 0, 0, 0);
    }
#pragma unroll
    for (int rr = 0; rr < 4; rr++)
        Z[(size_t)(tok0 + lq * 4 + rr) * R_ + lr] = acc[rr];

    // setup tail (grid-stride over segment-decoded float4 items)
    for (int i = blockIdx.x * 256 + t; i < SEG_TOT; i += 512 * 256) {
        if (i < SEG_E1) {
            float4 v = ((const float4*)E1_w)[i];
            ((ushort4*)E1b)[i] = make_ushort4(f2bf(v.x), f2bf(v.y), f2bf(v.z), f2bf(v.w));
        } else if (i < SEG_E1 + SEG_W) {
            int j = i - SEG_E1;
            float4 v = ((const float4*)C_w)[j];
            ((ushort4*)Cwb)[j] = make_ushort4(f2bf(v.x), f2bf(v.y), f2bf(v.z), f2bf(v.w));
        } else if (i < SEG_E1 + 2 * SEG_W) {
            int j = i - SEG_E1 - SEG_W;
            float4 v = ((const float4*)G_w)[j];
            ((ushort4*)Gwb)[j] = make_ushort4(f2bf(v.x), f2bf(v.y), f2bf(v.z), f2bf(v.w));
        } else if (i < SEG_E1 + 2 * SEG_W + SEG_Z) {
            int j = i - SEG_E1 - 2 * SEG_W;
            ((float4*)al_acc)[j] = make_float4(0.f, 0.f, 0.f, 0.f);
        } else {
            int j = (i - SEG_E1 - 2 * SEG_W - SEG_Z) * 4;
            tanhd[j + 0] = tanhf(a_delta[j + 0]);
            tanhd[j + 1] = tanhf(a_delta[j + 1]);
            tanhd[j + 2] = tanhf(a_delta[j + 2]);
            tanhd[j + 3] = tanhf(a_delta[j + 3]);
        }
    }
}

// ---------------------------------------------------------------------------
// Scans: 768 threads/block, ONE channel per thread (12 waves/block,
// 2 blocks/CU = 6 waves/SIMD for latency hiding). Same per-channel fp32
// math/order as before -> bitwise-identical results.
// ---------------------------------------------------------------------------
__device__ __forceinline__ void load_chunk_lds768(const float* __restrict__ Z,
                                                  const float* __restrict__ al_acc,
                                                  const float* __restrict__ E2b,
                                                  int tok0, int t,
                                                  float* Zs, float* als) {
    if (t < L_ * R_ / 4)      // 256 float4s
        ((float4*)Zs)[t] = ((const float4*)&Z[(size_t)tok0 * R_])[t];
    if (t < L_ * 3)           // 192
        als[t] = sigmoidf_(al_acc[(size_t)tok0 * 3 + t] + E2b[t % 3]);
}

__device__ __forceinline__ float dot16(const float* zrow, const float4* u) {
    float4 z0 = *(const float4*)&zrow[0],  z1 = *(const float4*)&zrow[4];
    float4 z2 = *(const float4*)&zrow[8],  z3 = *(const float4*)&zrow[12];
    return z0.x*u[0].x + z0.y*u[0].y + z0.z*u[0].z + z0.w*u[0].w
         + z1.x*u[1].x + z1.y*u[1].y + z1.z*u[1].z + z1.w*u[1].w
         + z2.x*u[2].x + z2.y*u[2].y + z2.z*u[2].z + z2.w*u[2].w
         + z3.x*u[3].x + z3.y*u[3].y + z3.z*u[3].z + z3.w*u[3].w;
}

__global__ __launch_bounds__(768, 2)
void scan_pass1(const float* __restrict__ Z, const float* __restrict__ al_acc,
                const float* __restrict__ E2b,
                const float* __restrict__ Uw, const float* __restrict__ a_base,
                const float* __restrict__ tanhd,
                float* __restrict__ Aagg, float* __restrict__ Send) {
    __shared__ float Zs[L_ * R_];
    __shared__ float als[L_ * 3];
    const int t = threadIdx.x;              // channel d = t
    const int c = blockIdx.x & (NC_ - 1);
    const int b = blockIdx.x >> 6;
    const int tok0 = b * T_ + c * L_;
    const int buck = t >> 8;
    load_chunk_lds768(Z, al_acc, E2b, tok0, t, Zs, als);

    float4 u[4];
#pragma unroll
    for (int q = 0; q < 4; q++)
        u[q] = *(const float4*)&Uw[(size_t)t * R_ + q * 4];
    float ab = a_base[t];
    float td = tanhd[t];
    __syncthreads();

    float a = 1.f, s = 0.f;
    for (int i = 0; i < L_; i++) {
        float av  = als[i * 3 + buck];
        float lam = sigmoidf_(fmaf(av, td, ab));
        float bu  = dot16(&Zs[i * R_], u);
        a *= lam;
        s = fmaf(lam, s, bu);
    }
    size_t o = ((size_t)(b * NC_ + c)) * D_ + t;
    Aagg[o] = a;
    Send[o] = s;
}

// pass3 with in-block carry computation (pass2 fused): the carry-in for
// chunk c is the prefix scan of Aagg/Send over chunks 0..c-1 (L2-resident,
// block-uniform trip count -> no divergence).
__global__ __launch_bounds__(768, 2)
void scan_pass3(const float* __restrict__ Z, const float* __restrict__ al_acc,
                const float* __restrict__ E2b,
                const float* __restrict__ Uw, const float* __restrict__ a_base,
                const float* __restrict__ tanhd,
                const float* __restrict__ Aagg, const float* __restrict__ Send,
                unsigned short* __restrict__ Sout) {
    __shared__ float Zs[L_ * R_];
    __shared__ float als[L_ * 3];
    const int t = threadIdx.x;              // channel d = t
    const int c = blockIdx.x & (NC_ - 1);
    const int b = blockIdx.x >> 6;
    const int tok0 = b * T_ + c * L_;
    const int buck = t >> 8;
    load_chunk_lds768(Z, al_acc, E2b, tok0, t, Zs, als);

    float4 u[4];
#pragma unroll
    for (int q = 0; q < 4; q++)
        u[q] = *(const float4*)&Uw[(size_t)t * R_ + q * 4];
    float ab = a_base[t];
    float td = tanhd[t];

    // carry-in: prefix over earlier chunks (pass2 fused in)
    float s = 0.f;
#pragma unroll 4
    for (int cc = 0; cc < c; ++cc) {
        size_t o = ((size_t)(b * NC_ + cc)) * D_ + t;
        s = fmaf(Aagg[o], s, Send[o]);
    }
    __syncthreads();

    for (int i = 0; i < L_; i++) {
        float av  = als[i * 3 + buck];
        float lam = sigmoidf_(fmaf(av, td, ab));
        float bu  = dot16(&Zs[i * R_], u);
        s = fmaf(lam, s, bu);
        Sout[(size_t)(tok0 + i) * D_ + t] = f2bf(s);
    }
}

// ---------------------------------------------------------------------------
extern "C" void kernel_launch(void* const* d_in, const int* in_sizes, int n_in,
                              void* d_out, int out_size, void* d_ws, size_t ws_size,
                              hipStream_t stream) {
    const float* x       = (const float*)d_in[0];
    const float* V_w     = (const float*)d_in[1];
    const float* U_w     = (const float*)d_in[2];
    const float* E1_w    = (const float*)d_in[3];
    const float* E1_b    = (const float*)d_in[4];
    const float* E2_w    = (const float*)d_in[5];
    const float* E2_b    = (const float*)d_in[6];
    const float* a_base  = (const float*)d_in[7];
    const float* a_delta = (const float*)d_in[8];
    const float* C_w     = (const float*)d_in[9];
    const float* G_w     = (const float*)d_in[10];
    const float* G_b     = (const float*)d_in[11];
    float* out = (float*)d_out;

    // workspace layout
    char* p = (char*)d_ws;
    float* Aagg   = (float*)p;          p += (size_t)B_ * NC_ * D_ * 4;
    float* Send   = (float*)p;          p += (size_t)B_ * NC_ * D_ * 4;
    float* tanhd  = (float*)p;          p += (size_t)D_ * 4;
    float* Z      = (float*)p;          p += (size_t)N_ * R_ * 4;
    float* al_acc = (float*)p;          p += (size_t)N_ * 3 * 4;
    unsigned short* x_bf  = (unsigned short*)p; p += (size_t)N_ * D_ * 2;
    unsigned short* S_bf  = (unsigned short*)p; p += (size_t)N_ * D_ * 2;
    unsigned short* E1_bf = (unsigned short*)p; p += (size_t)DB_ * D_ * 2;
    unsigned short* Cw_bf = (unsigned short*)p; p += (size_t)D_ * D_ * 2;
    unsigned short* Gw_bf = (unsigned short*)p; p += (size_t)D_ * D_ * 2;

    // x -> bf16, Z = x@V^T, and all setup work in one launch
    cvtz_kernel<<<N_ / 64, 256, 0, stream>>>(x, V_w, x_bf, Z,
                                             E1_w, C_w, G_w, a_delta,
                                             E1_bf, Cw_bf, Gw_bf, al_acc, tanhd);

    // E1 GEMM with fused alpha partials (H never materialized), full chip
    gemm_e1_alpha<<<512, 512, 0, stream>>>(x_bf, E1_bf, E1_b, E2_w, al_acc);

    scan_pass1<<<B_ * NC_, 768, 0, stream>>>(Z, al_acc, E2_b, U_w, a_base, tanhd, Aagg, Send);
    scan_pass3<<<B_ * NC_, 768, 0, stream>>>(Z, al_acc, E2_b, U_w, a_base, tanhd, Aagg, Send, S_bf);

    gemm_fused_out<<<768, 512, 0, stream>>>(x_bf, Gw_bf, S_bf, Cw_bf, G_b, out);
}